// Round 4
// baseline (788.423 us; speedup 1.0000x reference)
//
#include <hip/hip_runtime.h>
#include <hip/hip_bf16.h>

#define NSESS 2048
#define NI 64      // I
#define LL 63      // L = I-1
#define EE 256
#define HH 128
#define GG 384     // 3H

typedef __attribute__((ext_vector_type(8))) short short8;
typedef __attribute__((ext_vector_type(4))) float f32x4;

static __device__ __forceinline__ unsigned short f2b(float f) {
  union { float f; unsigned u; } v; v.f = f;
  unsigned r = (v.u + 0x7FFFu + ((v.u >> 16) & 1u)) >> 16;
  return (unsigned short)r;
}
static __device__ __forceinline__ float b2f(unsigned short s) {
  union { unsigned u; float f; } v; v.u = ((unsigned)s) << 16;
  return v.f;
}
static __device__ __forceinline__ float lo16(unsigned u) {
  union { unsigned v; float f; } x; x.v = u << 16; return x.f;
}
static __device__ __forceinline__ float hi16(unsigned u) {
  union { unsigned v; float f; } x; x.v = u & 0xFFFF0000u; return x.f;
}
static __device__ __forceinline__ float sigmoidf_(float x) {
  return 1.f / (1.f + __expf(-x));
}
static __device__ __forceinline__ float tanhf_(float x) {
  x = fminf(fmaxf(x, -15.f), 15.f);
  float e = __expf(-2.f * x);
  return (1.f - e) / (1.f + e);
}

// ---------------- K1: per-session prep ----------------
__global__ __launch_bounds__(64) void prep_kernel(const int* __restrict__ item_id,
                                                  const int* __restrict__ eval_from,
                                                  const int* __restrict__ u_type,
                                                  int* __restrict__ len_in,
                                                  int* __restrict__ inp,
                                                  float* __restrict__ out) {
  int n = blockIdx.x;          // session
  int lane = threadIdx.x;      // 0..63
  int b = n >> 5, s = n & 31;
  int allow = (s >= eval_from[b]) ? 1 : 0;
  int id = item_id[n * NI + lane];
  if (id < 0) id = 0;
  id *= allow;
  unsigned long long m = __ballot(id != 0);
  int length = __popcll(m);
  int li = length - 1;
  int tv = __shfl(id, (length > 0) ? (length - 1) : 0, 64);
  int target = (length > 0) ? tv : 0;
  if (lane < LL) inp[n * LL + lane] = (lane < li) ? id : 0;
  if (lane == 0) {
    len_in[n] = li;
    out[NSESS * 256 + n] = (float)target;            // Output 1: target
    out[NSESS * 256 + NSESS + n] = (float)u_type[b]; // Output 2: u
  }
}

// ---------------- K2: weights -> bf16 ----------------
__global__ __launch_bounds__(256) void cvt_weights(const float* __restrict__ W_ih,
                                                   const float* __restrict__ W_hh,
                                                   unsigned short* __restrict__ Wb,
                                                   unsigned* __restrict__ Whb) {
  int i = blockIdx.x * 256 + threadIdx.x;   // 98304 threads
  Wb[i] = f2b(W_ih[i]);
  if (i < 24576) {  // 384*128/2 packed pairs of W_hh
    float a = W_hh[2 * i], b = W_hh[2 * i + 1];
    Whb[i] = (unsigned)f2b(a) | ((unsigned)f2b(b) << 16);
  }
}

// ---------------- K3: gi = emb[inp] @ W_ih^T + b_ih (MFMA bf16) ----------------
// M = 2048*63 = 129024 rows, N = 384, K = 256. 16x16 tiles; wave does 16 rows x all 24 col-tiles.
__global__ __launch_bounds__(256) void gemm_in(const float* __restrict__ emb,
                                               const unsigned short* __restrict__ Wb,
                                               const float* __restrict__ b_ih,
                                               const int* __restrict__ inp,
                                               unsigned short* __restrict__ gi) {
  int lane = threadIdx.x & 63, wv = threadIdx.x >> 6;
  int mtile = blockIdx.x * 4 + wv;     // 8064 total
  int m0 = mtile << 4;
  int row = lane & 15, kg = lane >> 4; // kg in 0..3
  int m = m0 + row;
  long rid = inp[m];
  const float* xrow = emb + rid * EE;
  const unsigned short* wptr = Wb + (long)row * EE + kg * 8;

  f32x4 acc[24];
#pragma unroll
  for (int nt = 0; nt < 24; ++nt) acc[nt] = (f32x4){0.f, 0.f, 0.f, 0.f};

  for (int e0 = 0; e0 < EE; e0 += 32) {
    float4 a0 = *(const float4*)(xrow + e0 + kg * 8);
    float4 a1 = *(const float4*)(xrow + e0 + kg * 8 + 4);
    short8 af;
    af[0] = (short)f2b(a0.x); af[1] = (short)f2b(a0.y);
    af[2] = (short)f2b(a0.z); af[3] = (short)f2b(a0.w);
    af[4] = (short)f2b(a1.x); af[5] = (short)f2b(a1.y);
    af[6] = (short)f2b(a1.z); af[7] = (short)f2b(a1.w);
#pragma unroll
    for (int nt = 0; nt < 24; ++nt) {
      short8 bfr = *(const short8*)(wptr + nt * 16 * EE + e0);
      acc[nt] = __builtin_amdgcn_mfma_f32_16x16x32_bf16(af, bfr, acc[nt], 0, 0, 0);
    }
  }
  // D layout: N-col = lane&15, M-row = (lane>>4)*4 + j   [measured m89/m91]
  int crow = kg * 4, ccol = row;
#pragma unroll
  for (int nt = 0; nt < 24; ++nt) {
    int g = nt * 16 + ccol;
    float bv = b_ih[g];
#pragma unroll
    for (int j = 0; j < 4; ++j) {
      gi[(long)(m0 + crow + j) * GG + g] = f2b(acc[nt][j] + bv);
    }
  }
}

// ---------------- K4: GRU recurrence (8 sessions/WG, 768 threads, weights in VGPRs) ----------------
__global__ __launch_bounds__(768) void gru_rec(const unsigned* __restrict__ Whb,
                                               const float* __restrict__ b_hh,
                                               const unsigned short* __restrict__ gi,
                                               const int* __restrict__ len_in,
                                               unsigned short* __restrict__ outs,
                                               float* __restrict__ ht,
                                               float* __restrict__ out) {
  __shared__ float hbuf[8 * HH];       // 4 KB
  __shared__ float rbuf[8 * HH];       // 4 KB
  __shared__ float zbuf[8 * HH];       // 4 KB

  int t = threadIdx.x;
  int sh = (t >= GG) ? 1 : 0;
  int g = t - sh * GG;                 // gate index 0..383
  int n0 = blockIdx.x * 8;

  // W_hh row for this gate: 128 bf16 = 64 packed u32, register-resident
  unsigned wreg[64];
  const uint4* wp = (const uint4*)(Whb + g * 64);
#pragma unroll
  for (int i = 0; i < 16; ++i) {
    uint4 v = wp[i];
    wreg[4 * i] = v.x; wreg[4 * i + 1] = v.y; wreg[4 * i + 2] = v.z; wreg[4 * i + 3] = v.w;
  }
  for (int idx = t; idx < 8 * HH; idx += 768) hbuf[idx] = 0.f;
  int li[4];
#pragma unroll
  for (int s = 0; s < 4; ++s) li[s] = len_in[n0 + sh * 4 + s];
  float bh = b_hh[g];
  __syncthreads();

  for (int step = 0; step < LL; ++step) {
    float acc[4] = {0.f, 0.f, 0.f, 0.f};
#pragma unroll
    for (int k4 = 0; k4 < 32; ++k4) {
      unsigned wa = wreg[2 * k4], wb = wreg[2 * k4 + 1];
      float w0 = lo16(wa), w1 = hi16(wa), w2 = lo16(wb), w3 = hi16(wb);
#pragma unroll
      for (int s = 0; s < 4; ++s) {
        const float4 h4 = *(const float4*)&hbuf[(sh * 4 + s) * HH + k4 * 4];
        acc[s] = fmaf(w0, h4.x, fmaf(w1, h4.y, fmaf(w2, h4.z, fmaf(w3, h4.w, acc[s]))));
      }
    }
    float giv[4];
#pragma unroll
    for (int s = 0; s < 4; ++s) {
      int n = n0 + sh * 4 + s;
      giv[s] = b2f(gi[((long)n * LL + step) * GG + g]);
    }
    if (g < 128) {
#pragma unroll
      for (int s = 0; s < 4; ++s)
        rbuf[(sh * 4 + s) * HH + g] = sigmoidf_(giv[s] + acc[s] + bh);
    } else if (g < 256) {
#pragma unroll
      for (int s = 0; s < 4; ++s)
        zbuf[(sh * 4 + s) * HH + (g - 128)] = sigmoidf_(giv[s] + acc[s] + bh);
    }
    __syncthreads();
    if (g >= 256) {
      int j = g - 256;
#pragma unroll
      for (int s = 0; s < 4; ++s) {
        int slocal = sh * 4 + s;
        float hn = acc[s] + bh;
        float nval = tanhf_(giv[s] + rbuf[slocal * HH + j] * hn);
        float z = zbuf[slocal * HH + j];
        float hold = hbuf[slocal * HH + j];
        float hnew = (1.f - z) * nval + z * hold;
        bool valid = (step < li[s]);
        hbuf[slocal * HH + j] = valid ? hnew : hold;
        int n = n0 + slocal;
        outs[((long)n * LL + step) * HH + j] = f2b(valid ? hnew : 0.f);
      }
    }
    __syncthreads();
  }
  if (g >= 256) {
    int j = g - 256;
#pragma unroll
    for (int s = 0; s < 4; ++s) {
      int slocal = sh * 4 + s;
      int n = n0 + slocal;
      float h = hbuf[slocal * HH + j];
      ht[(long)n * HH + j] = h;
      out[(long)n * 256 + 128 + j] = h;     // reps[:,128:256] = ht (f32)
    }
  }
}

// ---------------- K5: attention + c_loc ----------------
__global__ __launch_bounds__(512) void attn(const unsigned short* __restrict__ outs,
                                            const float* __restrict__ ht,
                                            const float* __restrict__ W_a1,
                                            const float* __restrict__ W_a2,
                                            const float* __restrict__ W_vt,
                                            const int* __restrict__ len_in,
                                            float* __restrict__ out) {
  __shared__ unsigned short o_l[LL * HH];  // 16128 B (bf16)
  __shared__ unsigned short wa1[HH * HH];  // [k][c] transposed, 32768 B
  __shared__ float q2s[HH];
  __shared__ float wvt[HH];
  __shared__ float hts[HH];
  __shared__ float alphas[64];

  int n = blockIdx.x;
  int t = threadIdx.x;
  int li = len_in[n];

  for (int idx = t; idx < (LL * HH) / 2; idx += 512)
    ((unsigned*)o_l)[idx] = ((const unsigned*)(outs + (long)n * LL * HH))[idx];
  for (int idx = t; idx < HH * HH; idx += 512) {
    int k = idx >> 7, c = idx & 127;
    wa1[k * HH + c] = f2b(W_a1[c * HH + k]);
  }
  if (t < HH) { hts[t] = ht[(long)n * HH + t]; wvt[t] = W_vt[t]; }
  __syncthreads();

  if (t < HH) {
    float a = 0.f;
    const float* w2 = W_a2 + t * HH;
    for (int k = 0; k < HH; ++k) a += hts[k] * w2[k];
    q2s[t] = a;
  }
  __syncthreads();

  int lane = t & 63, w = t >> 6;   // 8 waves
  for (int l = w; l < LL; l += 8) {
    float v0 = 0.f, v1 = 0.f;
    for (int k = 0; k < HH; ++k) {
      float ov = b2f(o_l[l * HH + k]);
      v0 = fmaf(ov, b2f(wa1[k * HH + lane]), v0);
      v1 = fmaf(ov, b2f(wa1[k * HH + lane + 64]), v1);
    }
    float s0 = sigmoidf_(v0 + q2s[lane]) * wvt[lane];
    float s1 = sigmoidf_(v1 + q2s[lane + 64]) * wvt[lane + 64];
    float sum = s0 + s1;
#pragma unroll
    for (int off = 32; off; off >>= 1) sum += __shfl_xor(sum, off, 64);
    if (lane == 0) alphas[l] = (l < li) ? sum : 0.f;
  }
  __syncthreads();

  if (t < HH) {
    float c = 0.f;
    for (int l = 0; l < LL; ++l) c = fmaf(alphas[l], b2f(o_l[l * HH + t]), c);
    out[(long)n * 256 + t] = c;              // reps[:,0:128] = c_loc (f32)
  }
}

extern "C" void kernel_launch(void* const* d_in, const int* in_sizes, int n_in,
                              void* d_out, int out_size, void* d_ws, size_t ws_size,
                              hipStream_t stream) {
  (void)in_sizes; (void)n_in; (void)out_size; (void)ws_size;
  const int* item_id   = (const int*)d_in[0];
  const int* eval_from = (const int*)d_in[1];
  const int* u_type    = (const int*)d_in[2];
  const float* emb     = (const float*)d_in[3];
  const float* W_ih    = (const float*)d_in[4];
  const float* W_hh    = (const float*)d_in[5];
  const float* b_ih    = (const float*)d_in[6];
  const float* b_hh    = (const float*)d_in[7];
  const float* W_a1    = (const float*)d_in[8];
  const float* W_a2    = (const float*)d_in[9];
  const float* W_vt    = (const float*)d_in[10];

  float* out = (float*)d_out;   // f32: reps[2048*256] | target[2048] | u[2048]
  char* ws = (char*)d_ws;
  int* len_in          = (int*)(ws + 0);                      //      8192 B
  int* inp             = (int*)(ws + 8192);                   //    516096 B
  unsigned short* Wb   = (unsigned short*)(ws + 524288);      //    196608 B
  unsigned* Whb        = (unsigned*)(ws + 720896);            //     98304 B
  float* ht            = (float*)(ws + 819200);               //   1048576 B
  unsigned short* gi   = (unsigned short*)(ws + 1867776);     //  99090432 B
  unsigned short* outs = (unsigned short*)(ws + 100958208);   //  33030144 B -> ends 133988352

  // Safety: if gru_rec ever fails to run, attn sees zeros, not stale garbage.
  hipMemsetAsync(outs, 0, 33030144, stream);

  prep_kernel<<<NSESS, 64, 0, stream>>>(item_id, eval_from, u_type, len_in, inp, out);
  cvt_weights<<<384, 256, 0, stream>>>(W_ih, W_hh, Wb, Whb);
  gemm_in<<<2016, 256, 0, stream>>>(emb, Wb, b_ih, inp, gi);
  gru_rec<<<NSESS / 8, 768, 0, stream>>>(Whb, b_hh, gi, len_in, outs, ht, out);
  attn<<<NSESS, 512, 0, stream>>>(outs, ht, W_a1, W_a2, W_vt, len_in, out);
}

// Round 5
// 493.518 us; speedup vs baseline: 1.5976x; 1.5976x over previous
//
#include <hip/hip_runtime.h>
#include <hip/hip_bf16.h>

#define NSESS 2048
#define NI 64      // I
#define LL 63      // L = I-1
#define EE 256
#define HH 128
#define GG 384     // 3H

typedef __attribute__((ext_vector_type(8))) short short8;
typedef __attribute__((ext_vector_type(4))) float f32x4;

static __device__ __forceinline__ unsigned short f2b(float f) {
  union { float f; unsigned u; } v; v.f = f;
  unsigned r = (v.u + 0x7FFFu + ((v.u >> 16) & 1u)) >> 16;
  return (unsigned short)r;
}
static __device__ __forceinline__ float b2f(unsigned short s) {
  union { unsigned u; float f; } v; v.u = ((unsigned)s) << 16;
  return v.f;
}
static __device__ __forceinline__ float sigmoidf_(float x) {
  return 1.f / (1.f + __expf(-x));
}
static __device__ __forceinline__ float tanhf_(float x) {
  x = fminf(fmaxf(x, -15.f), 15.f);
  float e = __expf(-2.f * x);
  return (1.f - e) / (1.f + e);
}

// ---------------- K1: per-session prep ----------------
__global__ __launch_bounds__(64) void prep_kernel(const int* __restrict__ item_id,
                                                  const int* __restrict__ eval_from,
                                                  const int* __restrict__ u_type,
                                                  int* __restrict__ len_in,
                                                  int* __restrict__ inp,
                                                  float* __restrict__ out) {
  int n = blockIdx.x;          // session
  int lane = threadIdx.x;      // 0..63
  int b = n >> 5, s = n & 31;
  int allow = (s >= eval_from[b]) ? 1 : 0;
  int id = item_id[n * NI + lane];
  if (id < 0) id = 0;
  id *= allow;
  unsigned long long m = __ballot(id != 0);
  int length = __popcll(m);
  int li = length - 1;
  int tv = __shfl(id, (length > 0) ? (length - 1) : 0, 64);
  int target = (length > 0) ? tv : 0;
  if (lane < LL) inp[n * LL + lane] = (lane < li) ? id : 0;
  if (lane == 0) {
    len_in[n] = li;
    out[NSESS * 256 + n] = (float)target;            // Output 1: target
    out[NSESS * 256 + NSESS + n] = (float)u_type[b]; // Output 2: u
  }
}

// ---------------- K2: weights -> bf16 ----------------
__global__ __launch_bounds__(256) void cvt_weights(const float* __restrict__ W_ih,
                                                   const float* __restrict__ W_hh,
                                                   unsigned short* __restrict__ Wb,
                                                   unsigned short* __restrict__ Whs) {
  int i = blockIdx.x * 256 + threadIdx.x;   // 98304 threads
  Wb[i] = f2b(W_ih[i]);
  if (i < GG * HH) Whs[i] = f2b(W_hh[i]);   // W_hh bf16 [384][128]
}

// ---------------- K3: gi = emb[inp] @ W_ih^T + b_ih (MFMA bf16) ----------------
// M = 2048*63 = 129024 rows, N = 384, K = 256. Wave does 16 rows x 24 col-tiles.
__global__ __launch_bounds__(256) void gemm_in(const float* __restrict__ emb,
                                               const unsigned short* __restrict__ Wb,
                                               const float* __restrict__ b_ih,
                                               const int* __restrict__ inp,
                                               unsigned short* __restrict__ gi) {
  int lane = threadIdx.x & 63, wv = threadIdx.x >> 6;
  int mtile = blockIdx.x * 4 + wv;     // 8064 total
  int m0 = mtile << 4;
  int row = lane & 15, kg = lane >> 4; // kg in 0..3
  int m = m0 + row;
  long rid = inp[m];
  const float* xrow = emb + rid * EE;
  const unsigned short* wptr = Wb + (long)row * EE + kg * 8;

  f32x4 acc[24];
#pragma unroll
  for (int nt = 0; nt < 24; ++nt) acc[nt] = (f32x4){0.f, 0.f, 0.f, 0.f};

  for (int e0 = 0; e0 < EE; e0 += 32) {
    float4 a0 = *(const float4*)(xrow + e0 + kg * 8);
    float4 a1 = *(const float4*)(xrow + e0 + kg * 8 + 4);
    short8 af;
    af[0] = (short)f2b(a0.x); af[1] = (short)f2b(a0.y);
    af[2] = (short)f2b(a0.z); af[3] = (short)f2b(a0.w);
    af[4] = (short)f2b(a1.x); af[5] = (short)f2b(a1.y);
    af[6] = (short)f2b(a1.z); af[7] = (short)f2b(a1.w);
#pragma unroll
    for (int nt = 0; nt < 24; ++nt) {
      short8 bfr = *(const short8*)(wptr + nt * 16 * EE + e0);
      acc[nt] = __builtin_amdgcn_mfma_f32_16x16x32_bf16(af, bfr, acc[nt], 0, 0, 0);
    }
  }
  // D layout: N-col = lane&15, M-row = (lane>>4)*4 + j   [verified: this kernel passed]
  int crow = kg * 4, ccol = row;
#pragma unroll
  for (int nt = 0; nt < 24; ++nt) {
    int g = nt * 16 + ccol;
    float bv = b_ih[g];
#pragma unroll
    for (int j = 0; j < 4; ++j) {
      gi[(long)(m0 + crow + j) * GG + g] = f2b(acc[nt][j] + bv);
    }
  }
}

// ---------------- K4: GRU recurrence via MFMA ----------------
// 128 WGs x 512 threads (8 waves). WG = 16 sessions, all 384 gates, 63 steps.
// Wave w owns gates [16w,16w+16) for r/z/n (3 N-tiles). W_hh B-frags in VGPRs.
// h exchanged per step via double-buffered LDS bf16 (1 barrier/step).
__global__ __launch_bounds__(512) void gru_mfma(const unsigned short* __restrict__ Whs,
                                                const float* __restrict__ b_hh,
                                                const unsigned short* __restrict__ gi,
                                                const int* __restrict__ len_in,
                                                unsigned short* __restrict__ outs,
                                                float* __restrict__ ht,
                                                float* __restrict__ out) {
  constexpr int KP = HH + 8;                 // padded row stride (u16)
  __shared__ unsigned short hbuf[2][16 * KP]; // 8704 B

  const int t = threadIdx.x;
  const int w = t >> 6;                      // wave 0..7
  const int lane = t & 63;
  const int ccol = lane & 15;                // N-col (gate) for C; M-row (session) for A-read
  const int kg = lane >> 4;                  // 0..3
  const int sbase = kg * 4;                  // session base of this lane's C regs
  const int n0 = blockIdx.x * 16;
  const int jh = w * 16 + ccol;              // h/gate-local index owned by this lane

  // zero h buffer 0
  for (int idx = t; idx < 16 * HH; idx += 512)
    hbuf[0][(idx >> 7) * KP + (idx & 127)] = 0;

  // B fragments (W_hh rows), [class r/z/n][k-chunk]
  short8 bfr[3][4];
#pragma unroll
  for (int cls = 0; cls < 3; ++cls) {
    const unsigned short* wrow = Whs + (long)(cls * HH + jh) * HH;
#pragma unroll
    for (int c = 0; c < 4; ++c)
      bfr[cls][c] = *(const short8*)(wrow + c * 32 + kg * 8);
  }
  float bh[3];
#pragma unroll
  for (int cls = 0; cls < 3; ++cls) bh[cls] = b_hh[cls * HH + jh];

  int li[4];
  const unsigned short* gp[4];
  unsigned short* op[4];
#pragma unroll
  for (int r = 0; r < 4; ++r) {
    int n = n0 + sbase + r;
    li[r] = len_in[n];
    gp[r] = gi + (long)n * LL * GG + jh;
    op[r] = outs + (long)n * LL * HH + jh;
  }
  float hold[4] = {0.f, 0.f, 0.f, 0.f};

  // prefetch gi for step 0
  float gcur[4][3];
#pragma unroll
  for (int r = 0; r < 4; ++r)
#pragma unroll
    for (int cls = 0; cls < 3; ++cls)
      gcur[r][cls] = b2f(gp[r][cls * HH]);

  __syncthreads();

  int cur = 0;
  for (int step = 0; step < LL; ++step) {
    // A fragments: full h from LDS (session = ccol, k-chunk c)
    short8 af[4];
    const unsigned short* hb = &hbuf[cur][0];
#pragma unroll
    for (int c = 0; c < 4; ++c)
      af[c] = *(const short8*)(hb + ccol * KP + c * 32 + kg * 8);

    // prefetch next step's gi
    float gnx[4][3];
    if (step + 1 < LL) {
#pragma unroll
      for (int r = 0; r < 4; ++r)
#pragma unroll
        for (int cls = 0; cls < 3; ++cls)
          gnx[r][cls] = b2f(gp[r][GG + cls * HH]);
    }

    // gh = h @ W_hh^T + b_hh for this wave's 16 gates x 3 classes
    f32x4 acc[3];
#pragma unroll
    for (int cls = 0; cls < 3; ++cls) {
      acc[cls] = (f32x4){bh[cls], bh[cls], bh[cls], bh[cls]};
#pragma unroll
      for (int c = 0; c < 4; ++c)
        acc[cls] = __builtin_amdgcn_mfma_f32_16x16x32_bf16(af[c], bfr[cls][c], acc[cls], 0, 0, 0);
    }

    // gates + state update; reg r -> session sbase+r
#pragma unroll
    for (int r = 0; r < 4; ++r) {
      float rr = sigmoidf_(gcur[r][0] + acc[0][r]);
      float zz = sigmoidf_(gcur[r][1] + acc[1][r]);
      float nn = tanhf_(gcur[r][2] + rr * acc[2][r]);
      float hnew = (1.f - zz) * nn + zz * hold[r];
      bool valid = step < li[r];
      hold[r] = valid ? hnew : hold[r];
      op[r][0] = f2b(valid ? hnew : 0.f);
      hbuf[cur ^ 1][(sbase + r) * KP + jh] = f2b(hold[r]);
    }
    __syncthreads();
    cur ^= 1;
#pragma unroll
    for (int r = 0; r < 4; ++r) {
      gp[r] += GG; op[r] += HH;
      if (step + 1 < LL) {
#pragma unroll
        for (int cls = 0; cls < 3; ++cls) gcur[r][cls] = gnx[r][cls];
      }
    }
  }

#pragma unroll
  for (int r = 0; r < 4; ++r) {
    int n = n0 + sbase + r;
    ht[(long)n * HH + jh] = hold[r];
    out[(long)n * 256 + HH + jh] = hold[r];   // reps[:,128:256] = hT
  }
}

// ---------------- K5: attention + c_loc ----------------
__global__ __launch_bounds__(512) void attn(const unsigned short* __restrict__ outs,
                                            const float* __restrict__ ht,
                                            const float* __restrict__ W_a1,
                                            const float* __restrict__ W_a2,
                                            const float* __restrict__ W_vt,
                                            const int* __restrict__ len_in,
                                            float* __restrict__ out) {
  __shared__ unsigned short o_l[LL * HH];  // 16128 B (bf16)
  __shared__ unsigned short wa1[HH * HH];  // [k][c] transposed, 32768 B
  __shared__ float q2s[HH];
  __shared__ float wvt[HH];
  __shared__ float hts[HH];
  __shared__ float alphas[64];

  int n = blockIdx.x;
  int t = threadIdx.x;
  int li = len_in[n];

  for (int idx = t; idx < (LL * HH) / 2; idx += 512)
    ((unsigned*)o_l)[idx] = ((const unsigned*)(outs + (long)n * LL * HH))[idx];
  for (int idx = t; idx < HH * HH; idx += 512) {
    int k = idx >> 7, c = idx & 127;
    wa1[k * HH + c] = f2b(W_a1[c * HH + k]);
  }
  if (t < HH) { hts[t] = ht[(long)n * HH + t]; wvt[t] = W_vt[t]; }
  __syncthreads();

  if (t < HH) {
    float a = 0.f;
    const float* w2 = W_a2 + t * HH;
    for (int k = 0; k < HH; ++k) a += hts[k] * w2[k];
    q2s[t] = a;
  }
  __syncthreads();

  int lane = t & 63, w = t >> 6;   // 8 waves
  for (int l = w; l < LL; l += 8) {
    float v0 = 0.f, v1 = 0.f;
    for (int k = 0; k < HH; ++k) {
      float ov = b2f(o_l[l * HH + k]);
      v0 = fmaf(ov, b2f(wa1[k * HH + lane]), v0);
      v1 = fmaf(ov, b2f(wa1[k * HH + lane + 64]), v1);
    }
    float s0 = sigmoidf_(v0 + q2s[lane]) * wvt[lane];
    float s1 = sigmoidf_(v1 + q2s[lane + 64]) * wvt[lane + 64];
    float sum = s0 + s1;
#pragma unroll
    for (int off = 32; off; off >>= 1) sum += __shfl_xor(sum, off, 64);
    if (lane == 0) alphas[l] = (l < li) ? sum : 0.f;
  }
  __syncthreads();

  if (t < HH) {
    float c = 0.f;
    for (int l = 0; l < LL; ++l) c = fmaf(alphas[l], b2f(o_l[l * HH + t]), c);
    out[(long)n * 256 + t] = c;              // reps[:,0:128] = c_loc
  }
}

extern "C" void kernel_launch(void* const* d_in, const int* in_sizes, int n_in,
                              void* d_out, int out_size, void* d_ws, size_t ws_size,
                              hipStream_t stream) {
  (void)in_sizes; (void)n_in; (void)out_size; (void)ws_size;
  const int* item_id   = (const int*)d_in[0];
  const int* eval_from = (const int*)d_in[1];
  const int* u_type    = (const int*)d_in[2];
  const float* emb     = (const float*)d_in[3];
  const float* W_ih    = (const float*)d_in[4];
  const float* W_hh    = (const float*)d_in[5];
  const float* b_ih    = (const float*)d_in[6];
  const float* b_hh    = (const float*)d_in[7];
  const float* W_a1    = (const float*)d_in[8];
  const float* W_a2    = (const float*)d_in[9];
  const float* W_vt    = (const float*)d_in[10];

  float* out = (float*)d_out;   // f32: reps[2048*256] | target[2048] | u[2048]
  char* ws = (char*)d_ws;
  int* len_in           = (int*)(ws + 0);                      //      8192 B
  int* inp              = (int*)(ws + 8192);                   //    516096 B
  unsigned short* Wb    = (unsigned short*)(ws + 524288);      //    196608 B
  unsigned short* Whs   = (unsigned short*)(ws + 720896);      //     98304 B
  float* ht             = (float*)(ws + 819200);               //   1048576 B
  unsigned short* gi    = (unsigned short*)(ws + 1867776);     //  99090432 B
  unsigned short* outs  = (unsigned short*)(ws + 100958208);   //  33030144 B

  prep_kernel<<<NSESS, 64, 0, stream>>>(item_id, eval_from, u_type, len_in, inp, out);
  cvt_weights<<<384, 256, 0, stream>>>(W_ih, W_hh, Wb, Whs);
  gemm_in<<<2016, 256, 0, stream>>>(emb, Wb, b_ih, inp, gi);
  gru_mfma<<<NSESS / 16, 512, 0, stream>>>(Whs, b_hh, gi, len_in, outs, ht, out);
  attn<<<NSESS, 512, 0, stream>>>(outs, ht, W_a1, W_a2, W_vt, len_in, out);
}

// Round 6
// 391.434 us; speedup vs baseline: 2.0142x; 1.2608x over previous
//
#include <hip/hip_runtime.h>
#include <hip/hip_bf16.h>

#define NSESS 2048
#define NI 64      // I
#define LL 63      // L = I-1
#define EE 256
#define HH 128
#define GG 384     // 3H

typedef __attribute__((ext_vector_type(8))) short short8;
typedef __attribute__((ext_vector_type(4))) float f32x4;

static __device__ __forceinline__ unsigned short f2b(float f) {
  union { float f; unsigned u; } v; v.f = f;
  unsigned r = (v.u + 0x7FFFu + ((v.u >> 16) & 1u)) >> 16;
  return (unsigned short)r;
}
static __device__ __forceinline__ float b2f(unsigned short s) {
  union { unsigned u; float f; } v; v.u = ((unsigned)s) << 16;
  return v.f;
}
static __device__ __forceinline__ float sigmoidf_(float x) {
  return 1.f / (1.f + __expf(-x));
}
static __device__ __forceinline__ float tanhf_(float x) {
  x = fminf(fmaxf(x, -15.f), 15.f);
  float e = __expf(-2.f * x);
  return (1.f - e) / (1.f + e);
}

// ---------------- K1: per-session prep ----------------
__global__ __launch_bounds__(64) void prep_kernel(const int* __restrict__ item_id,
                                                  const int* __restrict__ eval_from,
                                                  const int* __restrict__ u_type,
                                                  int* __restrict__ len_in,
                                                  int* __restrict__ inp,
                                                  float* __restrict__ out) {
  int n = blockIdx.x;          // session
  int lane = threadIdx.x;      // 0..63
  int b = n >> 5, s = n & 31;
  int allow = (s >= eval_from[b]) ? 1 : 0;
  int id = item_id[n * NI + lane];
  if (id < 0) id = 0;
  id *= allow;
  unsigned long long m = __ballot(id != 0);
  int length = __popcll(m);
  int li = length - 1;
  int tv = __shfl(id, (length > 0) ? (length - 1) : 0, 64);
  int target = (length > 0) ? tv : 0;
  if (lane < LL) inp[n * LL + lane] = (lane < li) ? id : 0;
  if (lane == 0) {
    len_in[n] = li;
    out[NSESS * 256 + n] = (float)target;            // Output 1: target
    out[NSESS * 256 + NSESS + n] = (float)u_type[b]; // Output 2: u
  }
}

// ---------------- K2: weights -> bf16 (+ W_a1 transpose) ----------------
__global__ __launch_bounds__(256) void cvt_weights(const float* __restrict__ W_ih,
                                                   const float* __restrict__ W_hh,
                                                   const float* __restrict__ W_a1,
                                                   unsigned short* __restrict__ Wb,
                                                   unsigned short* __restrict__ Whs,
                                                   unsigned short* __restrict__ Wa1T) {
  int i = blockIdx.x * 256 + threadIdx.x;   // 98304 threads
  Wb[i] = f2b(W_ih[i]);
  if (i < GG * HH) Whs[i] = f2b(W_hh[i]);   // W_hh bf16 [384][128]
  if (i < HH * HH) {                        // Wa1T[k][c] = W_a1[c][k]
    int c = i >> 7, k = i & 127;
    Wa1T[k * HH + c] = f2b(W_a1[i]);
  }
}

// ---------------- K3: gi = emb[inp] @ W_ih^T + b_ih (MFMA, LDS-staged W) ----------------
// 4032 blocks x 256 thr (4 waves). Wave: 1 M-tile (16 rows) x 12 N-tiles (192 gates).
// Waves 0,1 -> mtile A (gate halves 0,1); waves 2,3 -> mtile B.
// W staged per K-chunk of 64 into LDS (49152 B), 16B-block XOR swizzle.
__global__ __launch_bounds__(256, 4) void gemm_in(const float* __restrict__ emb,
                                                  const unsigned short* __restrict__ Wb,
                                                  const float* __restrict__ b_ih,
                                                  const int* __restrict__ inp,
                                                  unsigned short* __restrict__ gi) {
  __shared__ unsigned short Bsh[384 * 64];   // 49152 B

  const int t = threadIdx.x;
  const int lane = t & 63, w = t >> 6;
  const int mtile = blockIdx.x * 2 + (w >> 1);
  const int ghalf = (w & 1) * 192;
  const int m0 = mtile << 4;
  const int row = lane & 15, kg = lane >> 4;

  long rid = inp[m0 + row];
  const float* xrow = emb + rid * EE + kg * 8;

  // preload + convert full A slice (K=256): 8 k-steps, 32 VGPR
  short8 af[8];
#pragma unroll
  for (int ks = 0; ks < 8; ++ks) {
    float4 a0 = *(const float4*)(xrow + ks * 32);
    float4 a1 = *(const float4*)(xrow + ks * 32 + 4);
    short8 v;
    v[0] = (short)f2b(a0.x); v[1] = (short)f2b(a0.y);
    v[2] = (short)f2b(a0.z); v[3] = (short)f2b(a0.w);
    v[4] = (short)f2b(a1.x); v[5] = (short)f2b(a1.y);
    v[6] = (short)f2b(a1.z); v[7] = (short)f2b(a1.w);
    af[ks] = v;
  }
  float bias[12];
#pragma unroll
  for (int nt = 0; nt < 12; ++nt) bias[nt] = b_ih[ghalf + nt * 16 + row];

  f32x4 acc[12];
#pragma unroll
  for (int nt = 0; nt < 12; ++nt) acc[nt] = (f32x4){0.f, 0.f, 0.f, 0.f};

  for (int c = 0; c < 4; ++c) {
    if (c) __syncthreads();
    // stage Wb[:, c*64 .. +64) -> Bsh (swizzled): 3072 x 16B units
#pragma unroll
    for (int i = 0; i < 12; ++i) {
      int u = t + i * 256;
      int g = u >> 3, blk = u & 7;
      short8 src = *(const short8*)(Wb + g * EE + c * 64 + blk * 8);
      *(short8*)(Bsh + g * 64 + ((blk ^ (g & 7)) << 3)) = src;
    }
    __syncthreads();
#pragma unroll
    for (int ks2 = 0; ks2 < 2; ++ks2) {
#pragma unroll
      for (int nt = 0; nt < 12; ++nt) {
        int G = ghalf + nt * 16 + row;
        short8 bfr = *(const short8*)(Bsh + G * 64 + (((ks2 * 4 + kg) ^ (G & 7)) << 3));
        acc[nt] = __builtin_amdgcn_mfma_f32_16x16x32_bf16(af[c * 2 + ks2], bfr, acc[nt], 0, 0, 0);
      }
    }
  }

  // epilogue: bias + bf16, coalesced store via LDS transpose (reuse Bsh)
  __syncthreads();
  unsigned short* Csh = Bsh + w * 3200;    // 16 rows x 192, stride 200
#pragma unroll
  for (int nt = 0; nt < 12; ++nt) {
#pragma unroll
    for (int j = 0; j < 4; ++j)
      Csh[(kg * 4 + j) * 200 + nt * 16 + row] = f2b(acc[nt][j] + bias[nt]);
  }
  __syncthreads();
#pragma unroll
  for (int it = 0; it < 12; ++it) {
    int u = lane + it * 64;               // 768 x 8B units = 16 rows x 384B
    int m_l = u / 48, c4 = u % 48;
    uint2 v = *(const uint2*)(Csh + m_l * 200 + c4 * 4);
    *(uint2*)(gi + (long)(m0 + m_l) * GG + ghalf + c4 * 4) = v;
  }
}

// ---------------- K4: GRU recurrence via MFMA ----------------
// 128 WGs x 512 threads (8 waves). WG = 16 sessions, all 384 gates, 63 steps.
__global__ __launch_bounds__(512) void gru_mfma(const unsigned short* __restrict__ Whs,
                                                const float* __restrict__ b_hh,
                                                const unsigned short* __restrict__ gi,
                                                const int* __restrict__ len_in,
                                                unsigned short* __restrict__ outs,
                                                float* __restrict__ ht,
                                                float* __restrict__ out) {
  constexpr int KP = HH + 8;                 // padded row stride (u16)
  __shared__ unsigned short hbuf[2][16 * KP]; // 8704 B

  const int t = threadIdx.x;
  const int w = t >> 6;                      // wave 0..7
  const int lane = t & 63;
  const int ccol = lane & 15;
  const int kg = lane >> 4;
  const int sbase = kg * 4;
  const int n0 = blockIdx.x * 16;
  const int jh = w * 16 + ccol;

  for (int idx = t; idx < 16 * HH; idx += 512)
    hbuf[0][(idx >> 7) * KP + (idx & 127)] = 0;

  short8 bfr[3][4];
#pragma unroll
  for (int cls = 0; cls < 3; ++cls) {
    const unsigned short* wrow = Whs + (long)(cls * HH + jh) * HH;
#pragma unroll
    for (int c = 0; c < 4; ++c)
      bfr[cls][c] = *(const short8*)(wrow + c * 32 + kg * 8);
  }
  float bh[3];
#pragma unroll
  for (int cls = 0; cls < 3; ++cls) bh[cls] = b_hh[cls * HH + jh];

  int li[4];
  const unsigned short* gp[4];
  unsigned short* op[4];
#pragma unroll
  for (int r = 0; r < 4; ++r) {
    int n = n0 + sbase + r;
    li[r] = len_in[n];
    gp[r] = gi + (long)n * LL * GG + jh;
    op[r] = outs + (long)n * LL * HH + jh;
  }
  float hold[4] = {0.f, 0.f, 0.f, 0.f};

  float gcur[4][3];
#pragma unroll
  for (int r = 0; r < 4; ++r)
#pragma unroll
    for (int cls = 0; cls < 3; ++cls)
      gcur[r][cls] = b2f(gp[r][cls * HH]);

  __syncthreads();

  int cur = 0;
  for (int step = 0; step < LL; ++step) {
    short8 af[4];
    const unsigned short* hb = &hbuf[cur][0];
#pragma unroll
    for (int c = 0; c < 4; ++c)
      af[c] = *(const short8*)(hb + ccol * KP + c * 32 + kg * 8);

    float gnx[4][3];
    if (step + 1 < LL) {
#pragma unroll
      for (int r = 0; r < 4; ++r)
#pragma unroll
        for (int cls = 0; cls < 3; ++cls)
          gnx[r][cls] = b2f(gp[r][GG + cls * HH]);
    }

    f32x4 acc[3];
#pragma unroll
    for (int cls = 0; cls < 3; ++cls) {
      acc[cls] = (f32x4){bh[cls], bh[cls], bh[cls], bh[cls]};
#pragma unroll
      for (int c = 0; c < 4; ++c)
        acc[cls] = __builtin_amdgcn_mfma_f32_16x16x32_bf16(af[c], bfr[cls][c], acc[cls], 0, 0, 0);
    }

#pragma unroll
    for (int r = 0; r < 4; ++r) {
      float rr = sigmoidf_(gcur[r][0] + acc[0][r]);
      float zz = sigmoidf_(gcur[r][1] + acc[1][r]);
      float nn = tanhf_(gcur[r][2] + rr * acc[2][r]);
      float hnew = (1.f - zz) * nn + zz * hold[r];
      bool valid = step < li[r];
      hold[r] = valid ? hnew : hold[r];
      op[r][0] = f2b(valid ? hnew : 0.f);
      hbuf[cur ^ 1][(sbase + r) * KP + jh] = f2b(hold[r]);
    }
    __syncthreads();
    cur ^= 1;
#pragma unroll
    for (int r = 0; r < 4; ++r) {
      gp[r] += GG; op[r] += HH;
      if (step + 1 < LL) {
#pragma unroll
        for (int cls = 0; cls < 3; ++cls) gcur[r][cls] = gnx[r][cls];
      }
    }
  }

#pragma unroll
  for (int r = 0; r < 4; ++r) {
    int n = n0 + sbase + r;
    ht[(long)n * HH + jh] = hold[r];
    out[(long)n * 256 + HH + jh] = hold[r];
  }
}

// ---------------- K5: attention + c_loc ----------------
__global__ __launch_bounds__(512) void attn(const unsigned short* __restrict__ outs,
                                            const float* __restrict__ ht,
                                            const unsigned short* __restrict__ Wa1T,
                                            const float* __restrict__ W_a2,
                                            const float* __restrict__ W_vt,
                                            const int* __restrict__ len_in,
                                            float* __restrict__ out) {
  __shared__ unsigned short o_l[LL * HH];  // 16128 B (bf16)
  __shared__ unsigned short wa1[HH * HH];  // [k][c], 32768 B
  __shared__ float q2s[HH];
  __shared__ float wvt[HH];
  __shared__ float hts[HH];
  __shared__ float alphas[64];

  int n = blockIdx.x;
  int t = threadIdx.x;
  int li = len_in[n];

  for (int idx = t; idx < (LL * HH) / 2; idx += 512)
    ((unsigned*)o_l)[idx] = ((const unsigned*)(outs + (long)n * LL * HH))[idx];
  for (int idx = t; idx < (HH * HH) / 2; idx += 512)
    ((unsigned*)wa1)[idx] = ((const unsigned*)Wa1T)[idx];
  if (t < HH) { hts[t] = ht[(long)n * HH + t]; wvt[t] = W_vt[t]; }
  __syncthreads();

  if (t < HH) {
    float a = 0.f;
    const float* w2 = W_a2 + t * HH;
    for (int k = 0; k < HH; ++k) a += hts[k] * w2[k];
    q2s[t] = a;
  }
  __syncthreads();

  int lane = t & 63, w = t >> 6;   // 8 waves
  for (int l = w; l < LL; l += 8) {
    float v0 = 0.f, v1 = 0.f;
    for (int k = 0; k < HH; ++k) {
      float ov = b2f(o_l[l * HH + k]);
      v0 = fmaf(ov, b2f(wa1[k * HH + lane]), v0);
      v1 = fmaf(ov, b2f(wa1[k * HH + lane + 64]), v1);
    }
    float s0 = sigmoidf_(v0 + q2s[lane]) * wvt[lane];
    float s1 = sigmoidf_(v1 + q2s[lane + 64]) * wvt[lane + 64];
    float sum = s0 + s1;
#pragma unroll
    for (int off = 32; off; off >>= 1) sum += __shfl_xor(sum, off, 64);
    if (lane == 0) alphas[l] = (l < li) ? sum : 0.f;
  }
  __syncthreads();

  if (t < HH) {
    float c = 0.f;
    for (int l = 0; l < LL; ++l) c = fmaf(alphas[l], b2f(o_l[l * HH + t]), c);
    out[(long)n * 256 + t] = c;
  }
}

extern "C" void kernel_launch(void* const* d_in, const int* in_sizes, int n_in,
                              void* d_out, int out_size, void* d_ws, size_t ws_size,
                              hipStream_t stream) {
  (void)in_sizes; (void)n_in; (void)out_size; (void)ws_size;
  const int* item_id   = (const int*)d_in[0];
  const int* eval_from = (const int*)d_in[1];
  const int* u_type    = (const int*)d_in[2];
  const float* emb     = (const float*)d_in[3];
  const float* W_ih    = (const float*)d_in[4];
  const float* W_hh    = (const float*)d_in[5];
  const float* b_ih    = (const float*)d_in[6];
  const float* b_hh    = (const float*)d_in[7];
  const float* W_a1    = (const float*)d_in[8];
  const float* W_a2    = (const float*)d_in[9];
  const float* W_vt    = (const float*)d_in[10];

  float* out = (float*)d_out;   // f32: reps[2048*256] | target[2048] | u[2048]
  char* ws = (char*)d_ws;
  int* len_in           = (int*)(ws + 0);                      //      8192 B
  int* inp              = (int*)(ws + 8192);                   //    516096 B
  unsigned short* Wb    = (unsigned short*)(ws + 524288);      //    196608 B
  unsigned short* Whs   = (unsigned short*)(ws + 720896);      //     98304 B
  float* ht             = (float*)(ws + 819200);               //   1048576 B
  unsigned short* gi    = (unsigned short*)(ws + 1867776);     //  99090432 B
  unsigned short* outs  = (unsigned short*)(ws + 100958208);   //  33030144 B -> ends 133988352
  unsigned short* Wa1T  = (unsigned short*)(ws + 133988352);   //     32768 B -> ends 134021120

  prep_kernel<<<NSESS, 64, 0, stream>>>(item_id, eval_from, u_type, len_in, inp, out);
  cvt_weights<<<384, 256, 0, stream>>>(W_ih, W_hh, W_a1, Wb, Whs, Wa1T);
  gemm_in<<<4032, 256, 0, stream>>>(emb, Wb, b_ih, inp, gi);
  gru_mfma<<<NSESS / 16, 512, 0, stream>>>(Whs, b_hh, gi, len_in, outs, ht, out);
  attn<<<NSESS, 512, 0, stream>>>(outs, ht, Wa1T, W_a2, W_vt, len_in, out);
}

// Round 7
// 234.073 us; speedup vs baseline: 3.3683x; 1.6723x over previous
//
#include <hip/hip_runtime.h>
#include <hip/hip_bf16.h>

#define NSESS 2048
#define NI 64      // I
#define LL 63      // L = I-1
#define EE 256
#define HH 128
#define GG 384     // 3H

typedef __attribute__((ext_vector_type(8))) short short8;
typedef __attribute__((ext_vector_type(4))) float f32x4;

static __device__ __forceinline__ unsigned short f2b(float f) {
  union { float f; unsigned u; } v; v.f = f;
  unsigned r = (v.u + 0x7FFFu + ((v.u >> 16) & 1u)) >> 16;
  return (unsigned short)r;
}
static __device__ __forceinline__ float b2f(unsigned short s) {
  union { unsigned u; float f; } v; v.u = ((unsigned)s) << 16;
  return v.f;
}
static __device__ __forceinline__ float sigmoidf_(float x) {
  return 1.f / (1.f + __expf(-x));
}
static __device__ __forceinline__ float tanhf_(float x) {
  x = fminf(fmaxf(x, -15.f), 15.f);
  float e = __expf(-2.f * x);
  return (1.f - e) / (1.f + e);
}

// ---------------- K1: per-session prep ----------------
__global__ __launch_bounds__(64) void prep_kernel(const int* __restrict__ item_id,
                                                  const int* __restrict__ eval_from,
                                                  const int* __restrict__ u_type,
                                                  int* __restrict__ len_in,
                                                  int* __restrict__ inp,
                                                  float* __restrict__ out) {
  int n = blockIdx.x;          // session
  int lane = threadIdx.x;      // 0..63
  int b = n >> 5, s = n & 31;
  int allow = (s >= eval_from[b]) ? 1 : 0;
  int id = item_id[n * NI + lane];
  if (id < 0) id = 0;
  id *= allow;
  unsigned long long m = __ballot(id != 0);
  int length = __popcll(m);
  int li = length - 1;
  int tv = __shfl(id, (length > 0) ? (length - 1) : 0, 64);
  int target = (length > 0) ? tv : 0;
  if (lane < LL) inp[n * LL + lane] = (lane < li) ? id : 0;
  if (lane == 0) {
    len_in[n] = li;
    out[NSESS * 256 + n] = (float)target;            // Output 1: target
    out[NSESS * 256 + NSESS + n] = (float)u_type[b]; // Output 2: u
  }
}

// ---------------- K2: weights -> bf16 ----------------
__global__ __launch_bounds__(256) void cvt_weights(const float* __restrict__ W_ih,
                                                   const float* __restrict__ W_hh,
                                                   const float* __restrict__ W_a1,
                                                   unsigned short* __restrict__ Wb,
                                                   unsigned short* __restrict__ Whs,
                                                   unsigned short* __restrict__ Wa1b) {
  int i = blockIdx.x * 256 + threadIdx.x;   // 98304 threads
  Wb[i] = f2b(W_ih[i]);
  if (i < GG * HH) Whs[i] = f2b(W_hh[i]);   // W_hh bf16 [384][128]
  if (i < HH * HH) Wa1b[i] = f2b(W_a1[i]);  // W_a1 bf16 [kout][h] = [N][K]
}

// ---------------- K3: gi = emb[inp] @ W_ih^T + b_ih (MFMA, LDS-staged W) ----------------
// 4032 blocks x 256 thr (4 waves). Wave: 1 M-tile (16 rows) x 12 N-tiles (192 gates).
__global__ __launch_bounds__(256, 4) void gemm_in(const float* __restrict__ emb,
                                                  const unsigned short* __restrict__ Wb,
                                                  const float* __restrict__ b_ih,
                                                  const int* __restrict__ inp,
                                                  unsigned short* __restrict__ gi) {
  __shared__ unsigned short Bsh[384 * 64];   // 49152 B

  const int t = threadIdx.x;
  const int lane = t & 63, w = t >> 6;
  const int mtile = blockIdx.x * 2 + (w >> 1);
  const int ghalf = (w & 1) * 192;
  const int m0 = mtile << 4;
  const int row = lane & 15, kg = lane >> 4;

  long rid = inp[m0 + row];
  const float* xrow = emb + rid * EE + kg * 8;

  short8 af[8];
#pragma unroll
  for (int ks = 0; ks < 8; ++ks) {
    float4 a0 = *(const float4*)(xrow + ks * 32);
    float4 a1 = *(const float4*)(xrow + ks * 32 + 4);
    short8 v;
    v[0] = (short)f2b(a0.x); v[1] = (short)f2b(a0.y);
    v[2] = (short)f2b(a0.z); v[3] = (short)f2b(a0.w);
    v[4] = (short)f2b(a1.x); v[5] = (short)f2b(a1.y);
    v[6] = (short)f2b(a1.z); v[7] = (short)f2b(a1.w);
    af[ks] = v;
  }
  float bias[12];
#pragma unroll
  for (int nt = 0; nt < 12; ++nt) bias[nt] = b_ih[ghalf + nt * 16 + row];

  f32x4 acc[12];
#pragma unroll
  for (int nt = 0; nt < 12; ++nt) acc[nt] = (f32x4){0.f, 0.f, 0.f, 0.f};

  for (int c = 0; c < 4; ++c) {
    if (c) __syncthreads();
#pragma unroll
    for (int i = 0; i < 12; ++i) {
      int u = t + i * 256;
      int g = u >> 3, blk = u & 7;
      short8 src = *(const short8*)(Wb + g * EE + c * 64 + blk * 8);
      *(short8*)(Bsh + g * 64 + ((blk ^ (g & 7)) << 3)) = src;
    }
    __syncthreads();
#pragma unroll
    for (int ks2 = 0; ks2 < 2; ++ks2) {
#pragma unroll
      for (int nt = 0; nt < 12; ++nt) {
        int G = ghalf + nt * 16 + row;
        short8 bfr = *(const short8*)(Bsh + G * 64 + (((ks2 * 4 + kg) ^ (G & 7)) << 3));
        acc[nt] = __builtin_amdgcn_mfma_f32_16x16x32_bf16(af[c * 2 + ks2], bfr, acc[nt], 0, 0, 0);
      }
    }
  }

  __syncthreads();
  unsigned short* Csh = Bsh + w * 3200;    // 16 rows x 192, stride 200
#pragma unroll
  for (int nt = 0; nt < 12; ++nt) {
#pragma unroll
    for (int j = 0; j < 4; ++j)
      Csh[(kg * 4 + j) * 200 + nt * 16 + row] = f2b(acc[nt][j] + bias[nt]);
  }
  __syncthreads();
#pragma unroll
  for (int it = 0; it < 12; ++it) {
    int u = lane + it * 64;
    int m_l = u / 48, c4 = u % 48;
    uint2 v = *(const uint2*)(Csh + m_l * 200 + c4 * 4);
    *(uint2*)(gi + (long)(m0 + m_l) * GG + ghalf + c4 * 4) = v;
  }
}

// ---------------- K4: GRU recurrence via MFMA ----------------
__global__ __launch_bounds__(512) void gru_mfma(const unsigned short* __restrict__ Whs,
                                                const float* __restrict__ b_hh,
                                                const unsigned short* __restrict__ gi,
                                                const int* __restrict__ len_in,
                                                unsigned short* __restrict__ outs,
                                                float* __restrict__ ht,
                                                float* __restrict__ out) {
  constexpr int KP = HH + 8;
  __shared__ unsigned short hbuf[2][16 * KP];

  const int t = threadIdx.x;
  const int w = t >> 6;
  const int lane = t & 63;
  const int ccol = lane & 15;
  const int kg = lane >> 4;
  const int sbase = kg * 4;
  const int n0 = blockIdx.x * 16;
  const int jh = w * 16 + ccol;

  for (int idx = t; idx < 16 * HH; idx += 512)
    hbuf[0][(idx >> 7) * KP + (idx & 127)] = 0;

  short8 bfr[3][4];
#pragma unroll
  for (int cls = 0; cls < 3; ++cls) {
    const unsigned short* wrow = Whs + (long)(cls * HH + jh) * HH;
#pragma unroll
    for (int c = 0; c < 4; ++c)
      bfr[cls][c] = *(const short8*)(wrow + c * 32 + kg * 8);
  }
  float bh[3];
#pragma unroll
  for (int cls = 0; cls < 3; ++cls) bh[cls] = b_hh[cls * HH + jh];

  int li[4];
  const unsigned short* gp[4];
  unsigned short* op[4];
#pragma unroll
  for (int r = 0; r < 4; ++r) {
    int n = n0 + sbase + r;
    li[r] = len_in[n];
    gp[r] = gi + (long)n * LL * GG + jh;
    op[r] = outs + (long)n * LL * HH + jh;
  }
  float hold[4] = {0.f, 0.f, 0.f, 0.f};

  float gcur[4][3];
#pragma unroll
  for (int r = 0; r < 4; ++r)
#pragma unroll
    for (int cls = 0; cls < 3; ++cls)
      gcur[r][cls] = b2f(gp[r][cls * HH]);

  __syncthreads();

  int cur = 0;
  for (int step = 0; step < LL; ++step) {
    short8 af[4];
    const unsigned short* hb = &hbuf[cur][0];
#pragma unroll
    for (int c = 0; c < 4; ++c)
      af[c] = *(const short8*)(hb + ccol * KP + c * 32 + kg * 8);

    float gnx[4][3];
    if (step + 1 < LL) {
#pragma unroll
      for (int r = 0; r < 4; ++r)
#pragma unroll
        for (int cls = 0; cls < 3; ++cls)
          gnx[r][cls] = b2f(gp[r][GG + cls * HH]);
    }

    f32x4 acc[3];
#pragma unroll
    for (int cls = 0; cls < 3; ++cls) {
      acc[cls] = (f32x4){bh[cls], bh[cls], bh[cls], bh[cls]};
#pragma unroll
      for (int c = 0; c < 4; ++c)
        acc[cls] = __builtin_amdgcn_mfma_f32_16x16x32_bf16(af[c], bfr[cls][c], acc[cls], 0, 0, 0);
    }

#pragma unroll
    for (int r = 0; r < 4; ++r) {
      float rr = sigmoidf_(gcur[r][0] + acc[0][r]);
      float zz = sigmoidf_(gcur[r][1] + acc[1][r]);
      float nn = tanhf_(gcur[r][2] + rr * acc[2][r]);
      float hnew = (1.f - zz) * nn + zz * hold[r];
      bool valid = step < li[r];
      hold[r] = valid ? hnew : hold[r];
      op[r][0] = f2b(valid ? hnew : 0.f);
      hbuf[cur ^ 1][(sbase + r) * KP + jh] = f2b(hold[r]);
    }
    __syncthreads();
    cur ^= 1;
#pragma unroll
    for (int r = 0; r < 4; ++r) {
      gp[r] += GG; op[r] += HH;
      if (step + 1 < LL) {
#pragma unroll
        for (int cls = 0; cls < 3; ++cls) gcur[r][cls] = gnx[r][cls];
      }
    }
  }

#pragma unroll
  for (int r = 0; r < 4; ++r) {
    int n = n0 + sbase + r;
    ht[(long)n * HH + jh] = hold[r];
    out[(long)n * 256 + HH + jh] = hold[r];
  }
}

// ---------------- K5: attention via MFMA ----------------
// 2048 blocks x 256 thr (4 waves) = 1 session. q1 = o_l[63x128] @ Wa1b^T via MFMA;
// alpha row-sum via shfl_xor in 16-lane col groups; c_loc on VALU.
__global__ __launch_bounds__(256) void attn(const unsigned short* __restrict__ outs,
                                            const float* __restrict__ ht,
                                            const unsigned short* __restrict__ Wa1b,
                                            const float* __restrict__ W_a2,
                                            const float* __restrict__ W_vt,
                                            const int* __restrict__ len_in,
                                            float* __restrict__ out) {
  constexpr int OP = HH + 8;               // padded row stride (u16)
  __shared__ unsigned short o_l[64 * OP];  // 17408 B
  __shared__ float q2s[HH];
  __shared__ float wvt[HH];
  __shared__ float hts[HH];
  __shared__ float aw[4][64];              // per-wave alpha partials
  __shared__ float alphas[64];

  const int n = blockIdx.x;
  const int t = threadIdx.x;
  const int lane = t & 63, wv = t >> 6;
  const int ccol = lane & 15, kg = lane >> 4;
  const int li = len_in[n];

  // o_l rows 0..62 from outs (u32 vectorized); row 63 zeroed
  const unsigned* src = (const unsigned*)(outs + (long)n * LL * HH);
  for (int idx = t; idx < LL * 64; idx += 256) {
    int r = idx >> 6, c2 = idx & 63;
    ((unsigned*)(o_l + r * OP))[c2] = src[r * 64 + c2];
  }
  if (t < 64) ((unsigned*)(o_l + 63 * OP))[t] = 0;
  if (t < HH) { hts[t] = ht[(long)n * HH + t]; wvt[t] = W_vt[t]; }

  // B-frags: wave wv owns cols [wv*32, wv*32+32)
  short8 bfr[2][4];
#pragma unroll
  for (int nt = 0; nt < 2; ++nt) {
    int G = wv * 32 + nt * 16 + ccol;
#pragma unroll
    for (int c = 0; c < 4; ++c)
      bfr[nt][c] = *(const short8*)(Wa1b + (long)G * HH + c * 32 + kg * 8);
  }
  __syncthreads();

  if (t < HH) {
    float a = 0.f;
    const float* w2 = W_a2 + t * HH;
    for (int k = 0; k < HH; ++k) a += hts[k] * w2[k];
    q2s[t] = a;
  }
  __syncthreads();

  // q1 MFMA: 4 M-tiles x 2 N-tiles x 4 k-chunks
  f32x4 acc[4][2];
#pragma unroll
  for (int mt = 0; mt < 4; ++mt)
#pragma unroll
    for (int nt = 0; nt < 2; ++nt) acc[mt][nt] = (f32x4){0.f, 0.f, 0.f, 0.f};
#pragma unroll
  for (int mt = 0; mt < 4; ++mt) {
#pragma unroll
    for (int c = 0; c < 4; ++c) {
      short8 af = *(const short8*)(o_l + (mt * 16 + ccol) * OP + c * 32 + kg * 8);
#pragma unroll
      for (int nt = 0; nt < 2; ++nt)
        acc[mt][nt] = __builtin_amdgcn_mfma_f32_16x16x32_bf16(af, bfr[nt][c], acc[mt][nt], 0, 0, 0);
    }
  }

  // alpha partial: row m = mt*16 + kg*4 + j, col = wv*32 + nt*16 + ccol
  float q2v[2], wvv[2];
#pragma unroll
  for (int nt = 0; nt < 2; ++nt) {
    int cg = wv * 32 + nt * 16 + ccol;
    q2v[nt] = q2s[cg]; wvv[nt] = wvt[cg];
  }
#pragma unroll
  for (int mt = 0; mt < 4; ++mt) {
    float part[4] = {0.f, 0.f, 0.f, 0.f};
#pragma unroll
    for (int nt = 0; nt < 2; ++nt)
#pragma unroll
      for (int j = 0; j < 4; ++j)
        part[j] += sigmoidf_(acc[mt][nt][j] + q2v[nt]) * wvv[nt];
    // reduce over 16 lanes sharing kg (lane ids kg*16 .. kg*16+15)
#pragma unroll
    for (int j = 0; j < 4; ++j) {
#pragma unroll
      for (int off = 1; off < 16; off <<= 1)
        part[j] += __shfl_xor(part[j], off, 64);
    }
    if (ccol == 0) {
#pragma unroll
      for (int j = 0; j < 4; ++j) aw[wv][mt * 16 + kg * 4 + j] = part[j];
    }
  }
  __syncthreads();

  if (t < 64) {
    float s = aw[0][t] + aw[1][t] + aw[2][t] + aw[3][t];
    alphas[t] = (t < li) ? s : 0.f;
  }
  __syncthreads();

  if (t < HH) {
    float c = 0.f;
    for (int l = 0; l < LL; ++l) c = fmaf(alphas[l], b2f(o_l[l * OP + t]), c);
    out[(long)n * 256 + t] = c;
  }
}

extern "C" void kernel_launch(void* const* d_in, const int* in_sizes, int n_in,
                              void* d_out, int out_size, void* d_ws, size_t ws_size,
                              hipStream_t stream) {
  (void)in_sizes; (void)n_in; (void)out_size; (void)ws_size;
  const int* item_id   = (const int*)d_in[0];
  const int* eval_from = (const int*)d_in[1];
  const int* u_type    = (const int*)d_in[2];
  const float* emb     = (const float*)d_in[3];
  const float* W_ih    = (const float*)d_in[4];
  const float* W_hh    = (const float*)d_in[5];
  const float* b_ih    = (const float*)d_in[6];
  const float* b_hh    = (const float*)d_in[7];
  const float* W_a1    = (const float*)d_in[8];
  const float* W_a2    = (const float*)d_in[9];
  const float* W_vt    = (const float*)d_in[10];

  float* out = (float*)d_out;   // f32: reps[2048*256] | target[2048] | u[2048]
  char* ws = (char*)d_ws;
  int* len_in           = (int*)(ws + 0);                      //      8192 B
  int* inp              = (int*)(ws + 8192);                   //    516096 B
  unsigned short* Wb    = (unsigned short*)(ws + 524288);      //    196608 B
  unsigned short* Whs   = (unsigned short*)(ws + 720896);      //     98304 B
  float* ht             = (float*)(ws + 819200);               //   1048576 B
  unsigned short* gi    = (unsigned short*)(ws + 1867776);     //  99090432 B
  unsigned short* outs  = (unsigned short*)(ws + 100958208);   //  33030144 B -> ends 133988352
  unsigned short* Wa1b  = (unsigned short*)(ws + 133988352);   //     32768 B -> ends 134021120

  prep_kernel<<<NSESS, 64, 0, stream>>>(item_id, eval_from, u_type, len_in, inp, out);
  cvt_weights<<<384, 256, 0, stream>>>(W_ih, W_hh, W_a1, Wb, Whs, Wa1b);
  gemm_in<<<4032, 256, 0, stream>>>(emb, Wb, b_ih, inp, gi);
  gru_mfma<<<NSESS / 16, 512, 0, stream>>>(Whs, b_hh, gi, len_in, outs, ht, out);
  attn<<<NSESS, 512, 0, stream>>>(outs, ht, Wa1b, W_a2, W_vt, len_in, out);
}

// Round 8
// 181.315 us; speedup vs baseline: 4.3483x; 1.2910x over previous
//
#include <hip/hip_runtime.h>
#include <hip/hip_bf16.h>

#define NSESS 2048
#define NI 64      // I
#define LL 63      // L = I-1
#define EE 256
#define HH 128
#define GG 384     // 3H

typedef __attribute__((ext_vector_type(8))) short short8;
typedef __attribute__((ext_vector_type(4))) float f32x4;

static __device__ __forceinline__ unsigned short f2b(float f) {
  union { float f; unsigned u; } v; v.f = f;
  unsigned r = (v.u + 0x7FFFu + ((v.u >> 16) & 1u)) >> 16;
  return (unsigned short)r;
}
static __device__ __forceinline__ float b2f(unsigned short s) {
  union { unsigned u; float f; } v; v.u = ((unsigned)s) << 16;
  return v.f;
}
static __device__ __forceinline__ float sigmoidf_(float x) {
  return 1.f / (1.f + __expf(-x));
}
static __device__ __forceinline__ float tanhf_(float x) {
  x = fminf(fmaxf(x, -15.f), 15.f);
  float e = __expf(-2.f * x);
  return (1.f - e) / (1.f + e);
}

// ---------------- K1: per-session prep ----------------
__global__ __launch_bounds__(64) void prep_kernel(const int* __restrict__ item_id,
                                                  const int* __restrict__ eval_from,
                                                  const int* __restrict__ u_type,
                                                  int* __restrict__ len_in,
                                                  int* __restrict__ inp,
                                                  float* __restrict__ out) {
  int n = blockIdx.x;          // session
  int lane = threadIdx.x;      // 0..63
  int b = n >> 5, s = n & 31;
  int allow = (s >= eval_from[b]) ? 1 : 0;
  int id = item_id[n * NI + lane];
  if (id < 0) id = 0;
  id *= allow;
  unsigned long long m = __ballot(id != 0);
  int length = __popcll(m);
  int li = length - 1;
  int tv = __shfl(id, (length > 0) ? (length - 1) : 0, 64);
  int target = (length > 0) ? tv : 0;
  if (lane < LL) inp[n * LL + lane] = (lane < li) ? id : 0;
  if (lane == 0) {
    len_in[n] = li;
    out[NSESS * 256 + n] = (float)target;            // Output 1: target
    out[NSESS * 256 + NSESS + n] = (float)u_type[b]; // Output 2: u
  }
}

// ---------------- K2: weights -> bf16 ----------------
__global__ __launch_bounds__(256) void cvt_weights(const float* __restrict__ W_ih,
                                                   const float* __restrict__ W_hh,
                                                   const float* __restrict__ W_a1,
                                                   unsigned short* __restrict__ Wb,
                                                   unsigned short* __restrict__ Whs,
                                                   unsigned short* __restrict__ Wa1b) {
  int i = blockIdx.x * 256 + threadIdx.x;   // 98304 threads
  Wb[i] = f2b(W_ih[i]);
  if (i < GG * HH) Whs[i] = f2b(W_hh[i]);   // W_hh bf16 [384][128]
  if (i < HH * HH) Wa1b[i] = f2b(W_a1[i]);  // W_a1 bf16 [N][K]
}

// ---------------- K3: gi = emb[inp] @ W_ih^T + b_ih ----------------
// 1008 blocks x 512 thr (8 waves). Wave owns gates [48w,48w+48) with W_ih
// register-resident (96 VGPR). Block grid-strides 8 M-tiles; A double-buffered
// in LDS with async-split staging (issue loads early, ds_write late, T14).
// 1 barrier per tile.
__global__ __launch_bounds__(512, 2) void gemm_in(const float* __restrict__ emb,
                                                  const unsigned short* __restrict__ Wb,
                                                  const float* __restrict__ b_ih,
                                                  const int* __restrict__ inp,
                                                  unsigned short* __restrict__ gi) {
  constexpr int XP = 264;                      // padded row stride (u16)
  __shared__ unsigned short Ash[2][16 * XP];   // 16896 B

  const int t = threadIdx.x;
  const int lane = t & 63, w = t >> 6;
  const int ccol = lane & 15, kg = lane >> 4;
  const int g0 = w * 48;

  // B fragments: gates g0..g0+47, full K=256
  short8 bfr[3][8];
#pragma unroll
  for (int nt = 0; nt < 3; ++nt) {
    const unsigned short* wrow = Wb + (long)(g0 + nt * 16 + ccol) * EE + kg * 8;
#pragma unroll
    for (int c = 0; c < 8; ++c) bfr[nt][c] = *(const short8*)(wrow + c * 32);
  }
  float bias[3];
#pragma unroll
  for (int nt = 0; nt < 3; ++nt) bias[nt] = b_ih[g0 + nt * 16 + ccol];

  const int tile0 = blockIdx.x * 8;
  const int srow = t >> 5;            // 0..15 (staging row)
  const int scol = (t & 31) * 8;      // f32 elem offset within row

  // stage tile 0 into Ash[0]
  {
    long rid = inp[tile0 * 16 + srow];
    const float* x = emb + rid * EE + scol;
    float4 a0 = *(const float4*)x, a1 = *(const float4*)(x + 4);
    short8 v;
    v[0]=(short)f2b(a0.x); v[1]=(short)f2b(a0.y); v[2]=(short)f2b(a0.z); v[3]=(short)f2b(a0.w);
    v[4]=(short)f2b(a1.x); v[5]=(short)f2b(a1.y); v[6]=(short)f2b(a1.z); v[7]=(short)f2b(a1.w);
    *(short8*)(&Ash[0][srow * XP + scol]) = v;
  }
  __syncthreads();

  for (int i = 0; i < 8; ++i) {
    const int cur = i & 1;
    const int m0 = (tile0 + i) * 16;

    // issue next tile's emb gather early (latency hides under MFMA below)
    float4 a0, a1;
    if (i + 1 < 8) {
      long rid = inp[(tile0 + i + 1) * 16 + srow];
      const float* x = emb + rid * EE + scol;
      a0 = *(const float4*)x; a1 = *(const float4*)(x + 4);
    }

    // compute tile i: 8 k-chunks x 3 N-tiles
    f32x4 acc[3];
#pragma unroll
    for (int nt = 0; nt < 3; ++nt)
      acc[nt] = (f32x4){bias[nt], bias[nt], bias[nt], bias[nt]};
#pragma unroll
    for (int c = 0; c < 8; ++c) {
      short8 af = *(const short8*)(&Ash[cur][ccol * XP + c * 32 + kg * 8]);
#pragma unroll
      for (int nt = 0; nt < 3; ++nt)
        acc[nt] = __builtin_amdgcn_mfma_f32_16x16x32_bf16(af, bfr[nt][c], acc[nt], 0, 0, 0);
    }

    // store: row = m0 + kg*4 + j, col = g0 + nt*16 + ccol
#pragma unroll
    for (int nt = 0; nt < 3; ++nt) {
      unsigned short* gout = gi + (long)(m0 + kg * 4) * GG + g0 + nt * 16 + ccol;
#pragma unroll
      for (int j = 0; j < 4; ++j) gout[j * GG] = f2b(acc[nt][j]);
    }

    // late half of stage: convert + LDS write into the other buffer
    if (i + 1 < 8) {
      short8 v;
      v[0]=(short)f2b(a0.x); v[1]=(short)f2b(a0.y); v[2]=(short)f2b(a0.z); v[3]=(short)f2b(a0.w);
      v[4]=(short)f2b(a1.x); v[5]=(short)f2b(a1.y); v[6]=(short)f2b(a1.z); v[7]=(short)f2b(a1.w);
      *(short8*)(&Ash[cur ^ 1][srow * XP + scol]) = v;
    }
    __syncthreads();
  }
}

// ---------------- K4: GRU recurrence via MFMA ----------------
__global__ __launch_bounds__(512) void gru_mfma(const unsigned short* __restrict__ Whs,
                                                const float* __restrict__ b_hh,
                                                const unsigned short* __restrict__ gi,
                                                const int* __restrict__ len_in,
                                                unsigned short* __restrict__ outs,
                                                float* __restrict__ ht,
                                                float* __restrict__ out) {
  constexpr int KP = HH + 8;
  __shared__ unsigned short hbuf[2][16 * KP];

  const int t = threadIdx.x;
  const int w = t >> 6;
  const int lane = t & 63;
  const int ccol = lane & 15;
  const int kg = lane >> 4;
  const int sbase = kg * 4;
  const int n0 = blockIdx.x * 16;
  const int jh = w * 16 + ccol;

  for (int idx = t; idx < 16 * HH; idx += 512)
    hbuf[0][(idx >> 7) * KP + (idx & 127)] = 0;

  short8 bfr[3][4];
#pragma unroll
  for (int cls = 0; cls < 3; ++cls) {
    const unsigned short* wrow = Whs + (long)(cls * HH + jh) * HH;
#pragma unroll
    for (int c = 0; c < 4; ++c)
      bfr[cls][c] = *(const short8*)(wrow + c * 32 + kg * 8);
  }
  float bh[3];
#pragma unroll
  for (int cls = 0; cls < 3; ++cls) bh[cls] = b_hh[cls * HH + jh];

  int li[4];
  const unsigned short* gp[4];
  unsigned short* op[4];
#pragma unroll
  for (int r = 0; r < 4; ++r) {
    int n = n0 + sbase + r;
    li[r] = len_in[n];
    gp[r] = gi + (long)n * LL * GG + jh;
    op[r] = outs + (long)n * LL * HH + jh;
  }
  float hold[4] = {0.f, 0.f, 0.f, 0.f};

  float gcur[4][3];
#pragma unroll
  for (int r = 0; r < 4; ++r)
#pragma unroll
    for (int cls = 0; cls < 3; ++cls)
      gcur[r][cls] = b2f(gp[r][cls * HH]);

  __syncthreads();

  int cur = 0;
  for (int step = 0; step < LL; ++step) {
    short8 af[4];
    const unsigned short* hb = &hbuf[cur][0];
#pragma unroll
    for (int c = 0; c < 4; ++c)
      af[c] = *(const short8*)(hb + ccol * KP + c * 32 + kg * 8);

    float gnx[4][3];
    if (step + 1 < LL) {
#pragma unroll
      for (int r = 0; r < 4; ++r)
#pragma unroll
        for (int cls = 0; cls < 3; ++cls)
          gnx[r][cls] = b2f(gp[r][GG + cls * HH]);
    }

    f32x4 acc[3];
#pragma unroll
    for (int cls = 0; cls < 3; ++cls) {
      acc[cls] = (f32x4){bh[cls], bh[cls], bh[cls], bh[cls]};
#pragma unroll
      for (int c = 0; c < 4; ++c)
        acc[cls] = __builtin_amdgcn_mfma_f32_16x16x32_bf16(af[c], bfr[cls][c], acc[cls], 0, 0, 0);
    }

#pragma unroll
    for (int r = 0; r < 4; ++r) {
      float rr = sigmoidf_(gcur[r][0] + acc[0][r]);
      float zz = sigmoidf_(gcur[r][1] + acc[1][r]);
      float nn = tanhf_(gcur[r][2] + rr * acc[2][r]);
      float hnew = (1.f - zz) * nn + zz * hold[r];
      bool valid = step < li[r];
      hold[r] = valid ? hnew : hold[r];
      op[r][0] = f2b(valid ? hnew : 0.f);
      hbuf[cur ^ 1][(sbase + r) * KP + jh] = f2b(hold[r]);
    }
    __syncthreads();
    cur ^= 1;
#pragma unroll
    for (int r = 0; r < 4; ++r) {
      gp[r] += GG; op[r] += HH;
      if (step + 1 < LL) {
#pragma unroll
        for (int cls = 0; cls < 3; ++cls) gcur[r][cls] = gnx[r][cls];
      }
    }
  }

#pragma unroll
  for (int r = 0; r < 4; ++r) {
    int n = n0 + sbase + r;
    ht[(long)n * HH + jh] = hold[r];
    out[(long)n * 256 + HH + jh] = hold[r];
  }
}

// ---------------- K5: attention via MFMA ----------------
__global__ __launch_bounds__(256) void attn(const unsigned short* __restrict__ outs,
                                            const float* __restrict__ ht,
                                            const unsigned short* __restrict__ Wa1b,
                                            const float* __restrict__ W_a2,
                                            const float* __restrict__ W_vt,
                                            const int* __restrict__ len_in,
                                            float* __restrict__ out) {
  constexpr int OP = HH + 8;               // padded row stride (u16)
  __shared__ unsigned short o_l[64 * OP];  // 17408 B
  __shared__ float q2s[HH];
  __shared__ float wvt[HH];
  __shared__ float hts[HH];
  __shared__ float aw[4][64];              // per-wave alpha partials
  __shared__ float alphas[64];

  const int n = blockIdx.x;
  const int t = threadIdx.x;
  const int lane = t & 63, wv = t >> 6;
  const int ccol = lane & 15, kg = lane >> 4;
  const int li = len_in[n];

  const unsigned* src = (const unsigned*)(outs + (long)n * LL * HH);
  for (int idx = t; idx < LL * 64; idx += 256) {
    int r = idx >> 6, c2 = idx & 63;
    ((unsigned*)(o_l + r * OP))[c2] = src[r * 64 + c2];
  }
  if (t < 64) ((unsigned*)(o_l + 63 * OP))[t] = 0;
  if (t < HH) { hts[t] = ht[(long)n * HH + t]; wvt[t] = W_vt[t]; }

  short8 bfr[2][4];
#pragma unroll
  for (int nt = 0; nt < 2; ++nt) {
    int G = wv * 32 + nt * 16 + ccol;
#pragma unroll
    for (int c = 0; c < 4; ++c)
      bfr[nt][c] = *(const short8*)(Wa1b + (long)G * HH + c * 32 + kg * 8);
  }
  __syncthreads();

  if (t < HH) {
    float a = 0.f;
    const float* w2 = W_a2 + t * HH;
    for (int k = 0; k < HH; ++k) a += hts[k] * w2[k];
    q2s[t] = a;
  }
  __syncthreads();

  f32x4 acc[4][2];
#pragma unroll
  for (int mt = 0; mt < 4; ++mt)
#pragma unroll
    for (int nt = 0; nt < 2; ++nt) acc[mt][nt] = (f32x4){0.f, 0.f, 0.f, 0.f};
#pragma unroll
  for (int mt = 0; mt < 4; ++mt) {
#pragma unroll
    for (int c = 0; c < 4; ++c) {
      short8 af = *(const short8*)(o_l + (mt * 16 + ccol) * OP + c * 32 + kg * 8);
#pragma unroll
      for (int nt = 0; nt < 2; ++nt)
        acc[mt][nt] = __builtin_amdgcn_mfma_f32_16x16x32_bf16(af, bfr[nt][c], acc[mt][nt], 0, 0, 0);
    }
  }

  float q2v[2], wvv[2];
#pragma unroll
  for (int nt = 0; nt < 2; ++nt) {
    int cg = wv * 32 + nt * 16 + ccol;
    q2v[nt] = q2s[cg]; wvv[nt] = wvt[cg];
  }
#pragma unroll
  for (int mt = 0; mt < 4; ++mt) {
    float part[4] = {0.f, 0.f, 0.f, 0.f};
#pragma unroll
    for (int nt = 0; nt < 2; ++nt)
#pragma unroll
      for (int j = 0; j < 4; ++j)
        part[j] += sigmoidf_(acc[mt][nt][j] + q2v[nt]) * wvv[nt];
#pragma unroll
    for (int j = 0; j < 4; ++j) {
#pragma unroll
      for (int off = 1; off < 16; off <<= 1)
        part[j] += __shfl_xor(part[j], off, 64);
    }
    if (ccol == 0) {
#pragma unroll
      for (int j = 0; j < 4; ++j) aw[wv][mt * 16 + kg * 4 + j] = part[j];
    }
  }
  __syncthreads();

  if (t < 64) {
    float s = aw[0][t] + aw[1][t] + aw[2][t] + aw[3][t];
    alphas[t] = (t < li) ? s : 0.f;
  }
  __syncthreads();

  if (t < HH) {
    float c = 0.f;
    for (int l = 0; l < LL; ++l) c = fmaf(alphas[l], b2f(o_l[l * OP + t]), c);
    out[(long)n * 256 + t] = c;
  }
}

extern "C" void kernel_launch(void* const* d_in, const int* in_sizes, int n_in,
                              void* d_out, int out_size, void* d_ws, size_t ws_size,
                              hipStream_t stream) {
  (void)in_sizes; (void)n_in; (void)out_size; (void)ws_size;
  const int* item_id   = (const int*)d_in[0];
  const int* eval_from = (const int*)d_in[1];
  const int* u_type    = (const int*)d_in[2];
  const float* emb     = (const float*)d_in[3];
  const float* W_ih    = (const float*)d_in[4];
  const float* W_hh    = (const float*)d_in[5];
  const float* b_ih    = (const float*)d_in[6];
  const float* b_hh    = (const float*)d_in[7];
  const float* W_a1    = (const float*)d_in[8];
  const float* W_a2    = (const float*)d_in[9];
  const float* W_vt    = (const float*)d_in[10];

  float* out = (float*)d_out;   // f32: reps[2048*256] | target[2048] | u[2048]
  char* ws = (char*)d_ws;
  int* len_in           = (int*)(ws + 0);                      //      8192 B
  int* inp              = (int*)(ws + 8192);                   //    516096 B
  unsigned short* Wb    = (unsigned short*)(ws + 524288);      //    196608 B
  unsigned short* Whs   = (unsigned short*)(ws + 720896);      //     98304 B
  float* ht             = (float*)(ws + 819200);               //   1048576 B
  unsigned short* gi    = (unsigned short*)(ws + 1867776);     //  99090432 B
  unsigned short* outs  = (unsigned short*)(ws + 100958208);   //  33030144 B -> ends 133988352
  unsigned short* Wa1b  = (unsigned short*)(ws + 133988352);   //     32768 B -> ends 134021120

  prep_kernel<<<NSESS, 64, 0, stream>>>(item_id, eval_from, u_type, len_in, inp, out);
  cvt_weights<<<384, 256, 0, stream>>>(W_ih, W_hh, W_a1, Wb, Whs, Wa1b);
  gemm_in<<<1008, 512, 0, stream>>>(emb, Wb, b_ih, inp, gi);
  gru_mfma<<<NSESS / 16, 512, 0, stream>>>(Whs, b_hh, gi, len_in, outs, ht, out);
  attn<<<NSESS, 512, 0, stream>>>(outs, ht, Wa1b, W_a2, W_vt, len_in, out);
}

// Round 9
// 175.102 us; speedup vs baseline: 4.5026x; 1.0355x over previous
//
#include <hip/hip_runtime.h>
#include <hip/hip_bf16.h>

#define NSESS 2048
#define NI 64      // I
#define LL 63      // L = I-1
#define EE 256
#define HH 128
#define GG 384     // 3H

typedef __attribute__((ext_vector_type(8))) short short8;
typedef __attribute__((ext_vector_type(4))) float f32x4;

static __device__ __forceinline__ unsigned short f2b(float f) {
  union { float f; unsigned u; } v; v.f = f;
  unsigned r = (v.u + 0x7FFFu + ((v.u >> 16) & 1u)) >> 16;
  return (unsigned short)r;
}
static __device__ __forceinline__ float b2f(unsigned short s) {
  union { unsigned u; float f; } v; v.u = ((unsigned)s) << 16;
  return v.f;
}
static __device__ __forceinline__ float sigmoidf_(float x) {
  return 1.f / (1.f + __expf(-x));
}
static __device__ __forceinline__ float tanhf_(float x) {
  x = fminf(fmaxf(x, -15.f), 15.f);
  float e = __expf(-2.f * x);
  return (1.f - e) / (1.f + e);
}
// LDS-only barrier: waits ds ops, does NOT drain vmcnt (raw s_barrier has no
// implicit drain — m201 pattern). Outstanding global loads/stores stay in flight.
static __device__ __forceinline__ void barrier_lds_only() {
  asm volatile("s_waitcnt lgkmcnt(0)" ::: "memory");
  __builtin_amdgcn_sched_barrier(0);
  __builtin_amdgcn_s_barrier();
  __builtin_amdgcn_sched_barrier(0);
}

// ---------------- K1: per-session prep ----------------
__global__ __launch_bounds__(64) void prep_kernel(const int* __restrict__ item_id,
                                                  const int* __restrict__ eval_from,
                                                  const int* __restrict__ u_type,
                                                  int* __restrict__ len_in,
                                                  int* __restrict__ inp,
                                                  float* __restrict__ out) {
  int n = blockIdx.x;          // session
  int lane = threadIdx.x;      // 0..63
  int b = n >> 5, s = n & 31;
  int allow = (s >= eval_from[b]) ? 1 : 0;
  int id = item_id[n * NI + lane];
  if (id < 0) id = 0;
  id *= allow;
  unsigned long long m = __ballot(id != 0);
  int length = __popcll(m);
  int li = length - 1;
  int tv = __shfl(id, (length > 0) ? (length - 1) : 0, 64);
  int target = (length > 0) ? tv : 0;
  if (lane < LL) inp[n * LL + lane] = (lane < li) ? id : 0;
  if (lane == 0) {
    len_in[n] = li;
    out[NSESS * 256 + n] = (float)target;            // Output 1: target
    out[NSESS * 256 + NSESS + n] = (float)u_type[b]; // Output 2: u
  }
}

// ---------------- K2: weights -> bf16 ----------------
__global__ __launch_bounds__(256) void cvt_weights(const float* __restrict__ W_ih,
                                                   const float* __restrict__ W_hh,
                                                   const float* __restrict__ W_a1,
                                                   unsigned short* __restrict__ Wb,
                                                   unsigned short* __restrict__ Whs,
                                                   unsigned short* __restrict__ Wa1b) {
  int i = blockIdx.x * 256 + threadIdx.x;   // 98304 threads
  Wb[i] = f2b(W_ih[i]);
  if (i < GG * HH) Whs[i] = f2b(W_hh[i]);   // W_hh bf16 [384][128]
  if (i < HH * HH) Wa1b[i] = f2b(W_a1[i]);  // W_a1 bf16 [N][K]
}

// ---------------- K3: gi = emb[inp] @ W_ih^T + b_ih ----------------
// 1008 blocks x 512 thr (8 waves). Wave owns gates [48w,48w+48), W_ih in VGPRs.
// Block grid-strides 8 M-tiles; A double-buffered in LDS, async-split staging,
// LDS-only barrier per tile (global loads/stores stay in flight across it).
__global__ __launch_bounds__(512, 2) void gemm_in(const float* __restrict__ emb,
                                                  const unsigned short* __restrict__ Wb,
                                                  const float* __restrict__ b_ih,
                                                  const int* __restrict__ inp,
                                                  unsigned short* __restrict__ gi) {
  constexpr int XP = 264;                      // padded row stride (u16)
  __shared__ unsigned short Ash[2][16 * XP];   // 16896 B

  const int t = threadIdx.x;
  const int lane = t & 63, w = t >> 6;
  const int ccol = lane & 15, kg = lane >> 4;
  const int g0 = w * 48;

  short8 bfr[3][8];
#pragma unroll
  for (int nt = 0; nt < 3; ++nt) {
    const unsigned short* wrow = Wb + (long)(g0 + nt * 16 + ccol) * EE + kg * 8;
#pragma unroll
    for (int c = 0; c < 8; ++c) bfr[nt][c] = *(const short8*)(wrow + c * 32);
  }
  float bias[3];
#pragma unroll
  for (int nt = 0; nt < 3; ++nt) bias[nt] = b_ih[g0 + nt * 16 + ccol];

  const int tile0 = blockIdx.x * 8;
  const int srow = t >> 5;            // 0..15 (staging row)
  const int scol = (t & 31) * 8;      // f32 elem offset within row

  {
    long rid = inp[tile0 * 16 + srow];
    const float* x = emb + rid * EE + scol;
    float4 a0 = *(const float4*)x, a1 = *(const float4*)(x + 4);
    short8 v;
    v[0]=(short)f2b(a0.x); v[1]=(short)f2b(a0.y); v[2]=(short)f2b(a0.z); v[3]=(short)f2b(a0.w);
    v[4]=(short)f2b(a1.x); v[5]=(short)f2b(a1.y); v[6]=(short)f2b(a1.z); v[7]=(short)f2b(a1.w);
    *(short8*)(&Ash[0][srow * XP + scol]) = v;
  }
  __syncthreads();

  for (int i = 0; i < 8; ++i) {
    const int cur = i & 1;
    const int m0 = (tile0 + i) * 16;

    float4 a0, a1;
    if (i + 1 < 8) {
      long rid = inp[(tile0 + i + 1) * 16 + srow];
      const float* x = emb + rid * EE + scol;
      a0 = *(const float4*)x; a1 = *(const float4*)(x + 4);
    }

    f32x4 acc[3];
#pragma unroll
    for (int nt = 0; nt < 3; ++nt)
      acc[nt] = (f32x4){bias[nt], bias[nt], bias[nt], bias[nt]};
#pragma unroll
    for (int c = 0; c < 8; ++c) {
      short8 af = *(const short8*)(&Ash[cur][ccol * XP + c * 32 + kg * 8]);
#pragma unroll
      for (int nt = 0; nt < 3; ++nt)
        acc[nt] = __builtin_amdgcn_mfma_f32_16x16x32_bf16(af, bfr[nt][c], acc[nt], 0, 0, 0);
    }

#pragma unroll
    for (int nt = 0; nt < 3; ++nt) {
      unsigned short* gout = gi + (long)(m0 + kg * 4) * GG + g0 + nt * 16 + ccol;
#pragma unroll
      for (int j = 0; j < 4; ++j) gout[j * GG] = f2b(acc[nt][j]);
    }

    if (i + 1 < 8) {
      short8 v;
      v[0]=(short)f2b(a0.x); v[1]=(short)f2b(a0.y); v[2]=(short)f2b(a0.z); v[3]=(short)f2b(a0.w);
      v[4]=(short)f2b(a1.x); v[5]=(short)f2b(a1.y); v[6]=(short)f2b(a1.z); v[7]=(short)f2b(a1.w);
      *(short8*)(&Ash[cur ^ 1][srow * XP + scol]) = v;
    }
    barrier_lds_only();
  }
}

// ---------------- K4: GRU recurrence via MFMA ----------------
// 128 WGs x 512 thr. WG = 16 sessions, wave owns 16 gate-cols x 3 classes.
// Per step: 1 LDS-only barrier; gi prefetch + outs stores float across it.
__global__ __launch_bounds__(512) void gru_mfma(const unsigned short* __restrict__ Whs,
                                                const float* __restrict__ b_hh,
                                                const unsigned short* __restrict__ gi,
                                                const int* __restrict__ len_in,
                                                unsigned short* __restrict__ outs,
                                                float* __restrict__ ht,
                                                float* __restrict__ out) {
  constexpr int KP = HH + 8;
  __shared__ unsigned short hbuf[2][16 * KP];

  const int t = threadIdx.x;
  const int w = t >> 6;
  const int lane = t & 63;
  const int ccol = lane & 15;
  const int kg = lane >> 4;
  const int sbase = kg * 4;
  const int n0 = blockIdx.x * 16;
  const int jh = w * 16 + ccol;

  for (int idx = t; idx < 16 * HH; idx += 512)
    hbuf[0][(idx >> 7) * KP + (idx & 127)] = 0;

  short8 bfr[3][4];
#pragma unroll
  for (int cls = 0; cls < 3; ++cls) {
    const unsigned short* wrow = Whs + (long)(cls * HH + jh) * HH;
#pragma unroll
    for (int c = 0; c < 4; ++c)
      bfr[cls][c] = *(const short8*)(wrow + c * 32 + kg * 8);
  }
  float bh[3];
#pragma unroll
  for (int cls = 0; cls < 3; ++cls) bh[cls] = b_hh[cls * HH + jh];

  int li[4];
  const unsigned short* gp[4];
  unsigned short* op[4];
#pragma unroll
  for (int r = 0; r < 4; ++r) {
    int n = n0 + sbase + r;
    li[r] = len_in[n];
    gp[r] = gi + (long)n * LL * GG + jh;
    op[r] = outs + (long)n * LL * HH + jh;
  }
  float hold[4] = {0.f, 0.f, 0.f, 0.f};

  float gcur[4][3];
#pragma unroll
  for (int r = 0; r < 4; ++r)
#pragma unroll
    for (int cls = 0; cls < 3; ++cls)
      gcur[r][cls] = b2f(gp[r][cls * HH]);

  __syncthreads();

  int cur = 0;
  for (int step = 0; step < LL; ++step) {
    short8 af[4];
    const unsigned short* hb = &hbuf[cur][0];
#pragma unroll
    for (int c = 0; c < 4; ++c)
      af[c] = *(const short8*)(hb + ccol * KP + c * 32 + kg * 8);

    float gnx[4][3];
    if (step + 1 < LL) {
#pragma unroll
      for (int r = 0; r < 4; ++r)
#pragma unroll
        for (int cls = 0; cls < 3; ++cls)
          gnx[r][cls] = b2f(gp[r][GG + cls * HH]);
    }

    f32x4 acc[3];
#pragma unroll
    for (int cls = 0; cls < 3; ++cls) {
      acc[cls] = (f32x4){bh[cls], bh[cls], bh[cls], bh[cls]};
#pragma unroll
      for (int c = 0; c < 4; ++c)
        acc[cls] = __builtin_amdgcn_mfma_f32_16x16x32_bf16(af[c], bfr[cls][c], acc[cls], 0, 0, 0);
    }

#pragma unroll
    for (int r = 0; r < 4; ++r) {
      float rr = sigmoidf_(gcur[r][0] + acc[0][r]);
      float zz = sigmoidf_(gcur[r][1] + acc[1][r]);
      float nn = tanhf_(gcur[r][2] + rr * acc[2][r]);
      float hnew = (1.f - zz) * nn + zz * hold[r];
      bool valid = step < li[r];
      hold[r] = valid ? hnew : hold[r];
      op[r][0] = f2b(valid ? hnew : 0.f);
      hbuf[cur ^ 1][(sbase + r) * KP + jh] = f2b(hold[r]);
    }
    barrier_lds_only();
    cur ^= 1;
#pragma unroll
    for (int r = 0; r < 4; ++r) {
      gp[r] += GG; op[r] += HH;
      if (step + 1 < LL) {
#pragma unroll
        for (int cls = 0; cls < 3; ++cls) gcur[r][cls] = gnx[r][cls];
      }
    }
  }

#pragma unroll
  for (int r = 0; r < 4; ++r) {
    int n = n0 + sbase + r;
    ht[(long)n * HH + jh] = hold[r];
    out[(long)n * 256 + HH + jh] = hold[r];
  }
}

// ---------------- K5: attention via MFMA ----------------
__global__ __launch_bounds__(256) void attn(const unsigned short* __restrict__ outs,
                                            const float* __restrict__ ht,
                                            const unsigned short* __restrict__ Wa1b,
                                            const float* __restrict__ W_a2,
                                            const float* __restrict__ W_vt,
                                            const int* __restrict__ len_in,
                                            float* __restrict__ out) {
  constexpr int OP = HH + 8;               // padded row stride (u16)
  __shared__ unsigned short o_l[64 * OP];  // 17408 B
  __shared__ float q2s[HH];
  __shared__ float wvt[HH];
  __shared__ float hts[HH];
  __shared__ float aw[4][64];              // per-wave alpha partials
  __shared__ float alphas[64];

  const int n = blockIdx.x;
  const int t = threadIdx.x;
  const int lane = t & 63, wv = t >> 6;
  const int ccol = lane & 15, kg = lane >> 4;
  const int li = len_in[n];

  const unsigned* src = (const unsigned*)(outs + (long)n * LL * HH);
  for (int idx = t; idx < LL * 64; idx += 256) {
    int r = idx >> 6, c2 = idx & 63;
    ((unsigned*)(o_l + r * OP))[c2] = src[r * 64 + c2];
  }
  if (t < 64) ((unsigned*)(o_l + 63 * OP))[t] = 0;
  if (t < HH) { hts[t] = ht[(long)n * HH + t]; wvt[t] = W_vt[t]; }

  short8 bfr[2][4];
#pragma unroll
  for (int nt = 0; nt < 2; ++nt) {
    int G = wv * 32 + nt * 16 + ccol;
#pragma unroll
    for (int c = 0; c < 4; ++c)
      bfr[nt][c] = *(const short8*)(Wa1b + (long)G * HH + c * 32 + kg * 8);
  }
  __syncthreads();

  if (t < HH) {
    float a = 0.f;
    const float* w2 = W_a2 + t * HH;
    for (int k = 0; k < HH; ++k) a += hts[k] * w2[k];
    q2s[t] = a;
  }
  __syncthreads();

  f32x4 acc[4][2];
#pragma unroll
  for (int mt = 0; mt < 4; ++mt)
#pragma unroll
    for (int nt = 0; nt < 2; ++nt) acc[mt][nt] = (f32x4){0.f, 0.f, 0.f, 0.f};
#pragma unroll
  for (int mt = 0; mt < 4; ++mt) {
#pragma unroll
    for (int c = 0; c < 4; ++c) {
      short8 af = *(const short8*)(o_l + (mt * 16 + ccol) * OP + c * 32 + kg * 8);
#pragma unroll
      for (int nt = 0; nt < 2; ++nt)
        acc[mt][nt] = __builtin_amdgcn_mfma_f32_16x16x32_bf16(af, bfr[nt][c], acc[mt][nt], 0, 0, 0);
    }
  }

  float q2v[2], wvv[2];
#pragma unroll
  for (int nt = 0; nt < 2; ++nt) {
    int cg = wv * 32 + nt * 16 + ccol;
    q2v[nt] = q2s[cg]; wvv[nt] = wvt[cg];
  }
#pragma unroll
  for (int mt = 0; mt < 4; ++mt) {
    float part[4] = {0.f, 0.f, 0.f, 0.f};
#pragma unroll
    for (int nt = 0; nt < 2; ++nt)
#pragma unroll
      for (int j = 0; j < 4; ++j)
        part[j] += sigmoidf_(acc[mt][nt][j] + q2v[nt]) * wvv[nt];
#pragma unroll
    for (int j = 0; j < 4; ++j) {
#pragma unroll
      for (int off = 1; off < 16; off <<= 1)
        part[j] += __shfl_xor(part[j], off, 64);
    }
    if (ccol == 0) {
#pragma unroll
      for (int j = 0; j < 4; ++j) aw[wv][mt * 16 + kg * 4 + j] = part[j];
    }
  }
  __syncthreads();

  if (t < 64) {
    float s = aw[0][t] + aw[1][t] + aw[2][t] + aw[3][t];
    alphas[t] = (t < li) ? s : 0.f;
  }
  __syncthreads();

  if (t < HH) {
    float c = 0.f;
    for (int l = 0; l < LL; ++l) c = fmaf(alphas[l], b2f(o_l[l * OP + t]), c);
    out[(long)n * 256 + t] = c;
  }
}

extern "C" void kernel_launch(void* const* d_in, const int* in_sizes, int n_in,
                              void* d_out, int out_size, void* d_ws, size_t ws_size,
                              hipStream_t stream) {
  (void)in_sizes; (void)n_in; (void)out_size; (void)ws_size;
  const int* item_id   = (const int*)d_in[0];
  const int* eval_from = (const int*)d_in[1];
  const int* u_type    = (const int*)d_in[2];
  const float* emb     = (const float*)d_in[3];
  const float* W_ih    = (const float*)d_in[4];
  const float* W_hh    = (const float*)d_in[5];
  const float* b_ih    = (const float*)d_in[6];
  const float* b_hh    = (const float*)d_in[7];
  const float* W_a1    = (const float*)d_in[8];
  const float* W_a2    = (const float*)d_in[9];
  const float* W_vt    = (const float*)d_in[10];

  float* out = (float*)d_out;   // f32: reps[2048*256] | target[2048] | u[2048]
  char* ws = (char*)d_ws;
  int* len_in           = (int*)(ws + 0);                      //      8192 B
  int* inp              = (int*)(ws + 8192);                   //    516096 B
  unsigned short* Wb    = (unsigned short*)(ws + 524288);      //    196608 B
  unsigned short* Whs   = (unsigned short*)(ws + 720896);      //     98304 B
  float* ht             = (float*)(ws + 819200);               //   1048576 B
  unsigned short* gi    = (unsigned short*)(ws + 1867776);     //  99090432 B
  unsigned short* outs  = (unsigned short*)(ws + 100958208);   //  33030144 B -> ends 133988352
  unsigned short* Wa1b  = (unsigned short*)(ws + 133988352);   //     32768 B -> ends 134021120

  prep_kernel<<<NSESS, 64, 0, stream>>>(item_id, eval_from, u_type, len_in, inp, out);
  cvt_weights<<<384, 256, 0, stream>>>(W_ih, W_hh, W_a1, Wb, Whs, Wa1b);
  gemm_in<<<1008, 512, 0, stream>>>(emb, Wb, b_ih, inp, gi);
  gru_mfma<<<NSESS / 16, 512, 0, stream>>>(Whs, b_hh, gi, len_in, outs, ht, out);
  attn<<<NSESS, 512, 0, stream>>>(outs, ht, Wa1b, W_a2, W_vt, len_in, out);
}

// Round 10
// 159.538 us; speedup vs baseline: 4.9419x; 1.0976x over previous
//
#include <hip/hip_runtime.h>
#include <hip/hip_bf16.h>

#define NSESS 2048
#define NI 64      // I
#define LL 63      // L = I-1
#define EE 256
#define HH 128
#define GG 384     // 3H

typedef __attribute__((ext_vector_type(8))) short short8;
typedef __attribute__((ext_vector_type(4))) float f32x4;

static __device__ __forceinline__ unsigned short f2b(float f) {
  union { float f; unsigned u; } v; v.f = f;
  unsigned r = (v.u + 0x7FFFu + ((v.u >> 16) & 1u)) >> 16;
  return (unsigned short)r;
}
static __device__ __forceinline__ float b2f(unsigned short s) {
  union { unsigned u; float f; } v; v.u = ((unsigned)s) << 16;
  return v.f;
}
static __device__ __forceinline__ float sigmoidf_(float x) {
  return 1.f / (1.f + __expf(-x));
}
static __device__ __forceinline__ float tanhf_(float x) {
  x = fminf(fmaxf(x, -15.f), 15.f);
  float e = __expf(-2.f * x);
  return (1.f - e) / (1.f + e);
}
// LDS-only barrier: waits ds ops, does NOT drain vmcnt.
static __device__ __forceinline__ void barrier_lds_only() {
  asm volatile("s_waitcnt lgkmcnt(0)" ::: "memory");
  __builtin_amdgcn_sched_barrier(0);
  __builtin_amdgcn_s_barrier();
  __builtin_amdgcn_sched_barrier(0);
}
// async global->LDS 16B (per-lane global addr, linear LDS dest)
static __device__ __forceinline__ void gload_lds16(const void* g, void* l) {
  __builtin_amdgcn_global_load_lds(
      (const __attribute__((address_space(1))) unsigned int*)g,
      (__attribute__((address_space(3))) unsigned int*)l, 16, 0, 0);
}

// ---------------- K1: per-session prep ----------------
__global__ __launch_bounds__(64) void prep_kernel(const int* __restrict__ item_id,
                                                  const int* __restrict__ eval_from,
                                                  const int* __restrict__ u_type,
                                                  int* __restrict__ len_in,
                                                  int* __restrict__ inp,
                                                  float* __restrict__ out) {
  int n = blockIdx.x;          // session
  int lane = threadIdx.x;      // 0..63
  int b = n >> 5, s = n & 31;
  int allow = (s >= eval_from[b]) ? 1 : 0;
  int id = item_id[n * NI + lane];
  if (id < 0) id = 0;
  id *= allow;
  unsigned long long m = __ballot(id != 0);
  int length = __popcll(m);
  int li = length - 1;
  int tv = __shfl(id, (length > 0) ? (length - 1) : 0, 64);
  int target = (length > 0) ? tv : 0;
  if (lane < LL) inp[n * LL + lane] = (lane < li) ? id : 0;
  if (lane == 0) {
    len_in[n] = li;
    out[NSESS * 256 + n] = (float)target;            // Output 1: target
    out[NSESS * 256 + NSESS + n] = (float)u_type[b]; // Output 2: u
  }
}

// ---------------- K2: weights -> bf16 ----------------
__global__ __launch_bounds__(256) void cvt_weights(const float* __restrict__ W_ih,
                                                   const float* __restrict__ W_hh,
                                                   const float* __restrict__ W_a1,
                                                   unsigned short* __restrict__ Wb,
                                                   unsigned short* __restrict__ Whs,
                                                   unsigned short* __restrict__ Wa1b) {
  int i = blockIdx.x * 256 + threadIdx.x;   // 98304 threads
  Wb[i] = f2b(W_ih[i]);
  if (i < GG * HH) Whs[i] = f2b(W_hh[i]);   // W_hh bf16 [384][128]
  if (i < HH * HH) Wa1b[i] = f2b(W_a1[i]);  // W_a1 bf16 [N][K]
}

// ---------------- K3: gi2 = emb[inp] @ W_ih^T + b_ih ----------------
// gi2 layout: [l][n][384] (step-major, for gru's coalesced LDS staging).
__global__ __launch_bounds__(512, 2) void gemm_in(const float* __restrict__ emb,
                                                  const unsigned short* __restrict__ Wb,
                                                  const float* __restrict__ b_ih,
                                                  const int* __restrict__ inp,
                                                  unsigned short* __restrict__ gi) {
  constexpr int XP = 264;                      // padded row stride (u16)
  __shared__ unsigned short Ash[2][16 * XP];   // 16896 B

  const int t = threadIdx.x;
  const int lane = t & 63, w = t >> 6;
  const int ccol = lane & 15, kg = lane >> 4;
  const int g0 = w * 48;

  short8 bfr[3][8];
#pragma unroll
  for (int nt = 0; nt < 3; ++nt) {
    const unsigned short* wrow = Wb + (long)(g0 + nt * 16 + ccol) * EE + kg * 8;
#pragma unroll
    for (int c = 0; c < 8; ++c) bfr[nt][c] = *(const short8*)(wrow + c * 32);
  }
  float bias[3];
#pragma unroll
  for (int nt = 0; nt < 3; ++nt) bias[nt] = b_ih[g0 + nt * 16 + ccol];

  const int tile0 = blockIdx.x * 8;
  const int srow = t >> 5;            // 0..15 (staging row)
  const int scol = (t & 31) * 8;      // f32 elem offset within row

  {
    long rid = inp[tile0 * 16 + srow];
    const float* x = emb + rid * EE + scol;
    float4 a0 = *(const float4*)x, a1 = *(const float4*)(x + 4);
    short8 v;
    v[0]=(short)f2b(a0.x); v[1]=(short)f2b(a0.y); v[2]=(short)f2b(a0.z); v[3]=(short)f2b(a0.w);
    v[4]=(short)f2b(a1.x); v[5]=(short)f2b(a1.y); v[6]=(short)f2b(a1.z); v[7]=(short)f2b(a1.w);
    *(short8*)(&Ash[0][srow * XP + scol]) = v;
  }
  __syncthreads();

  for (int i = 0; i < 8; ++i) {
    const int cur = i & 1;
    const int m0 = (tile0 + i) * 16;

    float4 a0, a1;
    if (i + 1 < 8) {
      long rid = inp[(tile0 + i + 1) * 16 + srow];
      const float* x = emb + rid * EE + scol;
      a0 = *(const float4*)x; a1 = *(const float4*)(x + 4);
    }

    f32x4 acc[3];
#pragma unroll
    for (int nt = 0; nt < 3; ++nt)
      acc[nt] = (f32x4){bias[nt], bias[nt], bias[nt], bias[nt]};
#pragma unroll
    for (int c = 0; c < 8; ++c) {
      short8 af = *(const short8*)(&Ash[cur][ccol * XP + c * 32 + kg * 8]);
#pragma unroll
      for (int nt = 0; nt < 3; ++nt)
        acc[nt] = __builtin_amdgcn_mfma_f32_16x16x32_bf16(af, bfr[nt][c], acc[nt], 0, 0, 0);
    }

    // store: row m = m0+kg*4+j -> (n = m/63, l = m%63); col g0+nt*16+ccol
    int nsd[4], lsd[4];
#pragma unroll
    for (int j = 0; j < 4; ++j) {
      int m = m0 + kg * 4 + j;
      nsd[j] = m / 63;
      lsd[j] = m - 63 * nsd[j];
    }
#pragma unroll
    for (int nt = 0; nt < 3; ++nt) {
      int g = g0 + nt * 16 + ccol;
#pragma unroll
      for (int j = 0; j < 4; ++j)
        gi[((long)lsd[j] * NSESS + nsd[j]) * GG + g] = f2b(acc[nt][j]);
    }

    if (i + 1 < 8) {
      short8 v;
      v[0]=(short)f2b(a0.x); v[1]=(short)f2b(a0.y); v[2]=(short)f2b(a0.z); v[3]=(short)f2b(a0.w);
      v[4]=(short)f2b(a1.x); v[5]=(short)f2b(a1.y); v[6]=(short)f2b(a1.z); v[7]=(short)f2b(a1.w);
      *(short8*)(&Ash[cur ^ 1][srow * XP + scol]) = v;
    }
    barrier_lds_only();
  }
}

// ---------------- K4: GRU recurrence via MFMA, fully LDS-resident loop ----------------
// 128 WGs x 512 thr (8 waves). WG = 16 sessions. 2-step windows:
//   gi slice [2][16][384] double-buffered in LDS (staged 2 windows ahead via
//   global_load_lds, counted vmcnt(4) at boundaries), h in a 2-slot XOR-swizzled
//   ring, outs dumped coalesced once per window. Inner loop: LDS+MFMA+VALU only.
__global__ __launch_bounds__(512) void gru_mfma(const unsigned short* __restrict__ Whs,
                                                const float* __restrict__ b_hh,
                                                const unsigned short* __restrict__ gi,
                                                const int* __restrict__ len_in,
                                                unsigned short* __restrict__ outs,
                                                float* __restrict__ ht,
                                                float* __restrict__ out) {
  __shared__ unsigned short Gbuf[2 * 12288];   // 49152 B: [buf][l2*16+n][384]
  __shared__ unsigned short ring[2 * 2048];    // 8192 B: [slot][16 sess][128], XOR-swz

  const int t = threadIdx.x;
  const int w = t >> 6, lane = t & 63;
  const int ccol = lane & 15, kg = lane >> 4;
  const int sbase = kg * 4;
  const int n0 = blockIdx.x * 16;
  const int jh = w * 16 + ccol;

  // B frags + biases (registers)
  short8 bfr[3][4];
#pragma unroll
  for (int cls = 0; cls < 3; ++cls) {
    const unsigned short* wrow = Whs + (long)(cls * HH + jh) * HH;
#pragma unroll
    for (int c = 0; c < 4; ++c)
      bfr[cls][c] = *(const short8*)(wrow + c * 32 + kg * 8);
  }
  float bh[3];
#pragma unroll
  for (int cls = 0; cls < 3; ++cls) bh[cls] = b_hh[cls * HH + jh];

  int li[4];
#pragma unroll
  for (int r = 0; r < 4; ++r) li[r] = len_in[n0 + sbase + r];
  const int lin_d = len_in[n0 + (t >> 5)];    // session for this thread's dump rows
  float hold[4] = {0.f, 0.f, 0.f, 0.f};

  // zero ring
  for (int idx = t; idx < 2 * 2048; idx += 512) ring[idx] = 0;

  // stage window W2 (2 steps x 16 sess x 384 u16 = 1536 x 16B units, 3/thread)
  auto do_stage = [&](int W2) {
    const int b = W2 & 1;
    const int l0s = W2 * 2;
#pragma unroll
    for (int i = 0; i < 3; ++i) {
      int u = i * 512 + t;
      int l2s = u / 768;
      int r1 = u - l2s * 768;
      int nn = r1 / 48;
      int seg = r1 - nn * 48;
      int lg = l0s + l2s; if (lg > 62) lg = 62;       // clamp (l=63 never read)
      const unsigned short* gsrc = gi + ((long)lg * NSESS + n0 + nn) * GG + seg * 8;
      gload_lds16(gsrc, (char*)Gbuf + b * 24576 + u * 16);
    }
  };

  do_stage(0);
  do_stage(1);
  asm volatile("s_waitcnt vmcnt(3)" ::: "memory");   // tail = stage(1)'s 3 loads
  __builtin_amdgcn_sched_barrier(0);
  barrier_lds_only();

  for (int W = 0; W < 32; ++W) {
    const int bsel = W & 1;
#pragma unroll
    for (int l2 = 0; l2 < 2; ++l2) {
      const int l = W * 2 + l2;
      if (l < LL) {
        // A frags from ring slot (l-1)&1, swizzled
        const unsigned short* rb = ring + ((l + 1) & 1) * 2048 + ccol * HH;
        short8 af[4];
#pragma unroll
        for (int c = 0; c < 4; ++c)
          af[c] = *(const short8*)(rb + ((c * 32 + kg * 8) ^ ((ccol & 7) << 3)));

        // gi from LDS
        const unsigned short* gb = Gbuf + bsel * 12288 + l2 * 6144;
        float gv[4][3];
#pragma unroll
        for (int r = 0; r < 4; ++r)
#pragma unroll
          for (int cls = 0; cls < 3; ++cls)
            gv[r][cls] = b2f(gb[(sbase + r) * GG + cls * HH + jh]);

        f32x4 acc[3];
#pragma unroll
        for (int cls = 0; cls < 3; ++cls) {
          acc[cls] = (f32x4){bh[cls], bh[cls], bh[cls], bh[cls]};
#pragma unroll
          for (int c = 0; c < 4; ++c)
            acc[cls] = __builtin_amdgcn_mfma_f32_16x16x32_bf16(af[c], bfr[cls][c], acc[cls], 0, 0, 0);
        }

        unsigned short* wrb = ring + (l & 1) * 2048;
#pragma unroll
        for (int r = 0; r < 4; ++r) {
          float rr = sigmoidf_(gv[r][0] + acc[0][r]);
          float zz = sigmoidf_(gv[r][1] + acc[1][r]);
          float nn = tanhf_(gv[r][2] + rr * acc[2][r]);
          float hnew = (1.f - zz) * nn + zz * hold[r];
          hold[r] = (l < li[r]) ? hnew : hold[r];
          int sess = sbase + r;
          wrb[sess * HH + (jh ^ ((sess & 7) << 3))] = f2b(hold[r]);
        }
        barrier_lds_only();
      }
    }

    // boundary: dump window's h to outs (1 coalesced 16B store/thread)
    {
      const int dn = t >> 5, dl2 = (t >> 4) & 1, dh = t & 15;
      const int dl = W * 2 + dl2;
      if (dl < LL) {
        short8 hv = *(const short8*)(ring + dl2 * 2048 + dn * HH + ((dh ^ (dn & 7)) << 3));
        if (dl >= lin_d) hv = (short8){0, 0, 0, 0, 0, 0, 0, 0};
        *(short8*)(outs + ((long)(n0 + dn) * LL + dl) * HH + dh * 8) = hv;
      }
    }
    if (W + 2 < 32) do_stage(W + 2);
    if (W < 30) {
      asm volatile("s_waitcnt vmcnt(4)" ::: "memory");  // tail = dump(1)+stage(3)
      __builtin_amdgcn_sched_barrier(0);
    } else if (W == 30) {
      asm volatile("s_waitcnt vmcnt(1)" ::: "memory");  // tail = dump(1)
      __builtin_amdgcn_sched_barrier(0);
    }
    if (W < 31) {
      __builtin_amdgcn_s_barrier();
      __builtin_amdgcn_sched_barrier(0);
    }
  }

#pragma unroll
  for (int r = 0; r < 4; ++r) {
    int n = n0 + sbase + r;
    ht[(long)n * HH + jh] = hold[r];
    out[(long)n * 256 + HH + jh] = hold[r];
  }
}

// ---------------- K5: attention via MFMA ----------------
__global__ __launch_bounds__(256) void attn(const unsigned short* __restrict__ outs,
                                            const float* __restrict__ ht,
                                            const unsigned short* __restrict__ Wa1b,
                                            const float* __restrict__ W_a2,
                                            const float* __restrict__ W_vt,
                                            const int* __restrict__ len_in,
                                            float* __restrict__ out) {
  constexpr int OP = HH + 8;               // padded row stride (u16)
  __shared__ unsigned short o_l[64 * OP];  // 17408 B
  __shared__ float q2s[HH];
  __shared__ float wvt[HH];
  __shared__ float hts[HH];
  __shared__ float aw[4][64];              // per-wave alpha partials
  __shared__ float alphas[64];

  const int n = blockIdx.x;
  const int t = threadIdx.x;
  const int lane = t & 63, wv = t >> 6;
  const int ccol = lane & 15, kg = lane >> 4;
  const int li = len_in[n];

  const unsigned* src = (const unsigned*)(outs + (long)n * LL * HH);
  for (int idx = t; idx < LL * 64; idx += 256) {
    int r = idx >> 6, c2 = idx & 63;
    ((unsigned*)(o_l + r * OP))[c2] = src[r * 64 + c2];
  }
  if (t < 64) ((unsigned*)(o_l + 63 * OP))[t] = 0;
  if (t < HH) { hts[t] = ht[(long)n * HH + t]; wvt[t] = W_vt[t]; }

  short8 bfr[2][4];
#pragma unroll
  for (int nt = 0; nt < 2; ++nt) {
    int G = wv * 32 + nt * 16 + ccol;
#pragma unroll
    for (int c = 0; c < 4; ++c)
      bfr[nt][c] = *(const short8*)(Wa1b + (long)G * HH + c * 32 + kg * 8);
  }
  __syncthreads();

  if (t < HH) {
    float a = 0.f;
    const float* w2 = W_a2 + t * HH;
    for (int k = 0; k < HH; ++k) a += hts[k] * w2[k];
    q2s[t] = a;
  }
  __syncthreads();

  f32x4 acc[4][2];
#pragma unroll
  for (int mt = 0; mt < 4; ++mt)
#pragma unroll
    for (int nt = 0; nt < 2; ++nt) acc[mt][nt] = (f32x4){0.f, 0.f, 0.f, 0.f};
#pragma unroll
  for (int mt = 0; mt < 4; ++mt) {
#pragma unroll
    for (int c = 0; c < 4; ++c) {
      short8 af = *(const short8*)(o_l + (mt * 16 + ccol) * OP + c * 32 + kg * 8);
#pragma unroll
      for (int nt = 0; nt < 2; ++nt)
        acc[mt][nt] = __builtin_amdgcn_mfma_f32_16x16x32_bf16(af, bfr[nt][c], acc[mt][nt], 0, 0, 0);
    }
  }

  float q2v[2], wvv[2];
#pragma unroll
  for (int nt = 0; nt < 2; ++nt) {
    int cg = wv * 32 + nt * 16 + ccol;
    q2v[nt] = q2s[cg]; wvv[nt] = wvt[cg];
  }
#pragma unroll
  for (int mt = 0; mt < 4; ++mt) {
    float part[4] = {0.f, 0.f, 0.f, 0.f};
#pragma unroll
    for (int nt = 0; nt < 2; ++nt)
#pragma unroll
      for (int j = 0; j < 4; ++j)
        part[j] += sigmoidf_(acc[mt][nt][j] + q2v[nt]) * wvv[nt];
#pragma unroll
    for (int j = 0; j < 4; ++j) {
#pragma unroll
      for (int off = 1; off < 16; off <<= 1)
        part[j] += __shfl_xor(part[j], off, 64);
    }
    if (ccol == 0) {
#pragma unroll
      for (int j = 0; j < 4; ++j) aw[wv][mt * 16 + kg * 4 + j] = part[j];
    }
  }
  __syncthreads();

  if (t < 64) {
    float s = aw[0][t] + aw[1][t] + aw[2][t] + aw[3][t];
    alphas[t] = (t < li) ? s : 0.f;
  }
  __syncthreads();

  if (t < HH) {
    float c = 0.f;
    for (int l = 0; l < LL; ++l) c = fmaf(alphas[l], b2f(o_l[l * OP + t]), c);
    out[(long)n * 256 + t] = c;
  }
}

extern "C" void kernel_launch(void* const* d_in, const int* in_sizes, int n_in,
                              void* d_out, int out_size, void* d_ws, size_t ws_size,
                              hipStream_t stream) {
  (void)in_sizes; (void)n_in; (void)out_size; (void)ws_size;
  const int* item_id   = (const int*)d_in[0];
  const int* eval_from = (const int*)d_in[1];
  const int* u_type    = (const int*)d_in[2];
  const float* emb     = (const float*)d_in[3];
  const float* W_ih    = (const float*)d_in[4];
  const float* W_hh    = (const float*)d_in[5];
  const float* b_ih    = (const float*)d_in[6];
  const float* b_hh    = (const float*)d_in[7];
  const float* W_a1    = (const float*)d_in[8];
  const float* W_a2    = (const float*)d_in[9];
  const float* W_vt    = (const float*)d_in[10];

  float* out = (float*)d_out;   // f32: reps[2048*256] | target[2048] | u[2048]
  char* ws = (char*)d_ws;
  int* len_in           = (int*)(ws + 0);                      //      8192 B
  int* inp              = (int*)(ws + 8192);                   //    516096 B
  unsigned short* Wb    = (unsigned short*)(ws + 524288);      //    196608 B
  unsigned short* Whs   = (unsigned short*)(ws + 720896);      //     98304 B
  float* ht             = (float*)(ws + 819200);               //   1048576 B
  unsigned short* gi    = (unsigned short*)(ws + 1867776);     //  99090432 B  [l][n][384]
  unsigned short* outs  = (unsigned short*)(ws + 100958208);   //  33030144 B -> ends 133988352
  unsigned short* Wa1b  = (unsigned short*)(ws + 133988352);   //     32768 B -> ends 134021120

  prep_kernel<<<NSESS, 64, 0, stream>>>(item_id, eval_from, u_type, len_in, inp, out);
  cvt_weights<<<384, 256, 0, stream>>>(W_ih, W_hh, W_a1, Wb, Whs, Wa1b);
  gemm_in<<<1008, 512, 0, stream>>>(emb, Wb, b_ih, inp, gi);
  gru_mfma<<<NSESS / 16, 512, 0, stream>>>(Whs, b_hh, gi, len_in, outs, ht, out);
  attn<<<NSESS, 512, 0, stream>>>(outs, ht, Wa1b, W_a2, W_vt, len_in, out);
}